// Round 7
// baseline (454.722 us; speedup 1.0000x reference)
//
#include <hip/hip_runtime.h>
#include <hip/hip_bf16.h>
#include <math.h>

typedef __hip_bfloat16 bf16;

#define NPIX 4096

__device__ __forceinline__ float b2f(bf16 v) { return __bfloat162float(v); }

__device__ __forceinline__ unsigned short f2bu(float f) {
    bf16 h = __float2bfloat16(f);
    return *(unsigned short*)&h;
}

// Wave-inline dtype detector: true if buffer is bf16. Uniform per wave.
__device__ __forceinline__ int detect_bf16(const unsigned short* __restrict__ qraw) {
    int lane = threadIdx.x & 63;
    unsigned short u = qraw[lane * 2];
    int e = (u >> 7) & 0xFF;
    unsigned long long ball = __ballot(e >= 100 && e <= 135);
    return __popcll(ball) > 32;
}

__device__ __forceinline__ float2 ld2f(const float* __restrict__ p) { return *(const float2*)p; }
__device__ __forceinline__ float2 ld2f(const bf16* __restrict__ p) {
    unsigned u = *(const unsigned*)p;
    return make_float2(__uint_as_float(u << 16), __uint_as_float(u & 0xFFFF0000u));
}
__device__ __forceinline__ float4 ld4f(const float* __restrict__ p) { return *(const float4*)p; }
__device__ __forceinline__ float4 ld4f(const bf16* __restrict__ p) {
    uint2 u = *(const uint2*)p;
    return make_float4(__uint_as_float(u.x << 16), __uint_as_float(u.x & 0xFFFF0000u),
                       __uint_as_float(u.y << 16), __uint_as_float(u.y & 0xFFFF0000u));
}

// dot of 12 bf16 (24B, 8B-aligned) with qv[12]
__device__ __forceinline__ float dot12(const bf16* __restrict__ row, const float* qv) {
    const uint2* s = (const uint2*)row;
    float d = 0.f;
#pragma unroll
    for (int c = 0; c < 3; ++c) {
        uint2 u = s[c];
        d += qv[c * 4 + 0] * __uint_as_float(u.x << 16);
        d += qv[c * 4 + 1] * __uint_as_float(u.x & 0xFFFF0000u);
        d += qv[c * 4 + 2] * __uint_as_float(u.y << 16);
        d += qv[c * 4 + 3] * __uint_as_float(u.y & 0xFFFF0000u);
    }
    return d;
}

__device__ __forceinline__ void acc12(float* ov, const bf16* __restrict__ row, float f) {
    const uint2* s = (const uint2*)row;
#pragma unroll
    for (int c = 0; c < 3; ++c) {
        uint2 u = s[c];
        ov[c * 4 + 0] += f * __uint_as_float(u.x << 16);
        ov[c * 4 + 1] += f * __uint_as_float(u.x & 0xFFFF0000u);
        ov[c * 4 + 2] += f * __uint_as_float(u.y << 16);
        ov[c * 4 + 3] += f * __uint_as_float(u.y & 0xFFFF0000u);
    }
}

// ---------------- convert 26 small tensors to fp32 ----------------
struct CArgs {
    const void* src[26];
    int dstoff[26];
    int n[26];
};

__global__ void convert_kernel(CArgs a, const unsigned short* __restrict__ qraw,
                               float* __restrict__ cw)
{
    const int isbf = detect_bf16(qraw);
    const int t = blockIdx.y;
    const int n = a.n[t];
    float* d = cw + a.dstoff[t];
    if (isbf) {
        const bf16* s = (const bf16*)a.src[t];
        for (int i = blockIdx.x * 256 + threadIdx.x; i < n; i += 256 * gridDim.x) d[i] = b2f(s[i]);
    } else {
        const float* s = (const float*)a.src[t];
        for (int i = blockIdx.x * 256 + threadIdx.x; i < n; i += 256 * gridDim.x) d[i] = s[i];
    }
}

// ---------------- conv1: 1x1, 436 -> 64, split-K(2) in block, 2 och x 2 px ----------------
template <typename T>
__device__ __forceinline__ void conv1_body(const T* __restrict__ q, const T* __restrict__ v0,
                                           const T* __restrict__ v1, int pix0, int og, int base,
                                           const float* __restrict__ w, float* acc)
{
    for (int i = base; i < base + 72; ++i) {
        float2 a = ld2f(q + i * NPIX + pix0);
        float w0 = w[og * 436 + i], w1 = w[(og + 1) * 436 + i];
        acc[0] += a.x * w0; acc[1] += a.y * w0;
        acc[2] += a.x * w1; acc[3] += a.y * w1;
    }
    for (int i = base; i < base + 72; ++i) {
        float2 a = ld2f(v0 + i * NPIX + pix0);
        float w0 = w[og * 436 + 144 + i], w1 = w[(og + 1) * 436 + 144 + i];
        acc[0] += a.x * w0; acc[1] += a.y * w0;
        acc[2] += a.x * w1; acc[3] += a.y * w1;
    }
    for (int i = base; i < base + 72; ++i) {
        float2 a = ld2f(v1 + i * NPIX + pix0);
        float w0 = w[og * 436 + 288 + i], w1 = w[(og + 1) * 436 + 288 + i];
        acc[0] += a.x * w0; acc[1] += a.y * w0;
        acc[2] += a.x * w1; acc[3] += a.y * w1;
    }
}

__global__ __launch_bounds__(256) void conv1_kernel(
    const void* __restrict__ q, const void* __restrict__ v0,
    const void* __restrict__ v1, const float* __restrict__ fl0,
    const float* __restrict__ fl1, const float* __restrict__ w,
    const float* __restrict__ b, float* __restrict__ out)
{
    __shared__ float red[128][4];
    const int isbf = detect_bf16((const unsigned short*)q);
    const int tid = threadIdx.x;
    const int lane = tid & 127, r = tid >> 7;
    const int og = blockIdx.y * 2;
    const int pix0 = (blockIdx.x * 128 + lane) * 2;
    float acc[4];
    if (r == 0) { acc[0] = b[og]; acc[1] = b[og]; acc[2] = b[og + 1]; acc[3] = b[og + 1]; }
    else        { acc[0] = 0.f;   acc[1] = 0.f;   acc[2] = 0.f;       acc[3] = 0.f; }
    const int base = r * 72;
    if (isbf) conv1_body<bf16>((const bf16*)q, (const bf16*)v0, (const bf16*)v1, pix0, og, base, w, acc);
    else      conv1_body<float>((const float*)q, (const float*)v0, (const float*)v1, pix0, og, base, w, acc);
    if (r == 0) {
        float fa[8] = { fl0[pix0], fl0[pix0 + 1], fl0[NPIX + pix0], fl0[NPIX + pix0 + 1],
                        fl1[pix0], fl1[pix0 + 1], fl1[NPIX + pix0], fl1[NPIX + pix0 + 1] };
#pragma unroll
        for (int i = 0; i < 4; ++i) {
            float w0 = w[og * 436 + 432 + i], w1 = w[(og + 1) * 436 + 432 + i];
            acc[0] += fa[i * 2] * w0; acc[1] += fa[i * 2 + 1] * w0;
            acc[2] += fa[i * 2] * w1; acc[3] += fa[i * 2 + 1] * w1;
        }
    }
    if (r == 1) { red[lane][0] = acc[0]; red[lane][1] = acc[1]; red[lane][2] = acc[2]; red[lane][3] = acc[3]; }
    __syncthreads();
    if (r == 0) {
        float a0 = acc[0] + red[lane][0], a1 = acc[1] + red[lane][1];
        float a2 = acc[2] + red[lane][2], a3 = acc[3] + red[lane][3];
        a0 = (a0 >= 0.f) ? a0 : 0.1f * a0;
        a1 = (a1 >= 0.f) ? a1 : 0.1f * a1;
        a2 = (a2 >= 0.f) ? a2 : 0.1f * a2;
        a3 = (a3 >= 0.f) ? a3 : 0.1f * a3;
        *(float2*)(out + og * NPIX + pix0) = make_float2(a0, a1);
        *(float2*)(out + (og + 1) * NPIX + pix0) = make_float2(a2, a3);
    }
}

// ---------------- conv 3x3, 64 -> 64, pad 1, lrelu, split-K(2), 2 och x 2 px ----------------
__global__ __launch_bounds__(256) void conv3_kernel(
    const float* __restrict__ in, const float* __restrict__ w,
    const float* __restrict__ b, float* __restrict__ out)
{
    __shared__ float red[128][4];
    const int tid = threadIdx.x;
    const int lane = tid & 127, r = tid >> 7;
    const int og = blockIdx.y * 2;
    const int pix0 = (blockIdx.x * 128 + lane) * 2;
    const int y = pix0 >> 6, x0 = pix0 & 63;

    const float lm = (x0 > 0) ? 1.f : 0.f;
    const float rm = (x0 < 62) ? 1.f : 0.f;
    const int lo = max(x0 - 1, 0), ro = min(x0 + 2, 63);

    float rmask[3]; int roff[3];
#pragma unroll
    for (int rr = 0; rr < 3; ++rr) {
        int yy = y + rr - 1;
        rmask[rr] = ((unsigned)yy < 64u) ? 1.f : 0.f;
        roff[rr] = min(max(yy, 0), 63) * 64;
    }

    float a00, a01, a10, a11;
    if (r == 0) { a00 = b[og]; a01 = b[og]; a10 = b[og + 1]; a11 = b[og + 1]; }
    else        { a00 = 0.f;   a01 = 0.f;   a10 = 0.f;       a11 = 0.f; }

    for (int ci = r * 32; ci < r * 32 + 32; ++ci) {
        const float* ib = in + ci * NPIX;
        float win[3][4];
#pragma unroll
        for (int rr = 0; rr < 3; ++rr) {
            const float* rp = ib + roff[rr];
            float2 f = *(const float2*)(rp + x0);
            float rmk = rmask[rr];
            win[rr][0] = rp[lo] * lm * rmk;
            win[rr][1] = f.x * rmk;
            win[rr][2] = f.y * rmk;
            win[rr][3] = rp[ro] * rm * rmk;
        }
        const float* w0 = w + og * 576 + ci * 9;
        const float* w1 = w0 + 576;
#pragma unroll
        for (int dy = 0; dy < 3; ++dy) {
#pragma unroll
            for (int dx = 0; dx < 3; ++dx) {
                float wt0 = w0[dy * 3 + dx], wt1 = w1[dy * 3 + dx];
                a00 += win[dy][dx] * wt0;     a01 += win[dy][dx + 1] * wt0;
                a10 += win[dy][dx] * wt1;     a11 += win[dy][dx + 1] * wt1;
            }
        }
    }
    if (r == 1) { red[lane][0] = a00; red[lane][1] = a01; red[lane][2] = a10; red[lane][3] = a11; }
    __syncthreads();
    if (r == 0) {
        a00 += red[lane][0]; a01 += red[lane][1]; a10 += red[lane][2]; a11 += red[lane][3];
        a00 = (a00 >= 0.f) ? a00 : 0.1f * a00;
        a01 = (a01 >= 0.f) ? a01 : 0.1f * a01;
        a10 = (a10 >= 0.f) ? a10 : 0.1f * a10;
        a11 = (a11 >= 0.f) ? a11 : 0.1f * a11;
        *(float2*)(out + og * NPIX + pix0) = make_float2(a00, a01);
        *(float2*)(out + (og + 1) * NPIX + pix0) = make_float2(a10, a11);
    }
}

// ---------------- conv6: 1x1, 64 -> 432, split-K(2), 8 out x 2 px ----------------
__global__ __launch_bounds__(256) void conv6_off_kernel(
    const float* __restrict__ in, const float* __restrict__ w,
    const float* __restrict__ b, const float* __restrict__ fl0,
    float* __restrict__ py, float* __restrict__ px)
{
    __shared__ float red[128][16];
    const int tid = threadIdx.x;
    const int lane = tid & 127, r = tid >> 7;
    const int obase = blockIdx.y * 8;
    const int pix0 = (blockIdx.x * 128 + lane) * 2;
    float acc[16];
#pragma unroll
    for (int j = 0; j < 8; ++j) {
        float bv = (r == 0) ? b[obase + j] : 0.f;
        acc[j * 2] = bv; acc[j * 2 + 1] = bv;
    }
    for (int i = r * 32; i < r * 32 + 32; ++i) {
        float2 a = *(const float2*)(in + i * NPIX + pix0);
#pragma unroll
        for (int j = 0; j < 8; ++j) {
            float wv = w[(obase + j) * 64 + i];
            acc[j * 2] += a.x * wv; acc[j * 2 + 1] += a.y * wv;
        }
    }
    if (r == 1) {
#pragma unroll
        for (int j = 0; j < 16; ++j) red[lane][j] = acc[j];
    }
    __syncthreads();
    if (r == 0) {
        const float fy0 = fl0[NPIX + pix0], fy1 = fl0[NPIX + pix0 + 1];
        const float fx0 = fl0[pix0], fx1 = fl0[pix0 + 1];
        const float yf = (float)(pix0 >> 6);
        const float xf0 = (float)(pix0 & 63), xf1 = xf0 + 1.f;
#pragma unroll
        for (int j = 0; j < 8; ++j) {
            int o = obase + j;
            float v0 = 10.f * tanhf(acc[j * 2] + red[lane][j * 2]);
            float v1 = 10.f * tanhf(acc[j * 2 + 1] + red[lane][j * 2 + 1]);
            int s = o >> 1;
            int a_idx = s % 9;
            if ((o & 1) == 0) {
                float base = (float)(a_idx / 3 - 1) + yf;
                *(float2*)(py + s * NPIX + pix0) = make_float2(v0 + fy0 + base, v1 + fy1 + base);
            } else {
                float base = (float)(a_idx % 3 - 1);
                *(float2*)(px + s * NPIX + pix0) = make_float2(v0 + fx0 + base + xf0, v1 + fx1 + base + xf1);
            }
        }
    }
}

// ---------------- fused q/k/v projection: 5 z-slices, split-K(2), 8 out x 4 px ----------------
struct PS { const void* src; const float* w; const float* b; bf16* dst; int clip; };
struct PArgs { PS s[5]; };

template <typename T>
__device__ __forceinline__ void proj_body(const T* __restrict__ ib, int pix0, int og, int base,
                                          const float* __restrict__ w, float* acc)
{
    for (int i = base; i < base + 72; ++i) {
        float4 a = ld4f(ib + i * NPIX + pix0);
#pragma unroll
        for (int j = 0; j < 8; ++j) {
            float wv = w[i * 288 + og + j];
            acc[j * 4 + 0] += a.x * wv;
            acc[j * 4 + 1] += a.y * wv;
            acc[j * 4 + 2] += a.z * wv;
            acc[j * 4 + 3] += a.w * wv;
        }
    }
}

__global__ __launch_bounds__(256) void proj_kernel(PArgs pa, const unsigned short* __restrict__ qraw)
{
    __shared__ float red[128][32];
    const int isbf = detect_bf16(qraw);
    const PS ps = pa.s[blockIdx.z];
    const int tid = threadIdx.x;
    const int lane = tid & 127, r = tid >> 7;
    const int og = blockIdx.y * 8;
    const int pix0 = (blockIdx.x * 128 + lane) * 4;
    float acc[32];
#pragma unroll
    for (int j = 0; j < 8; ++j) {
        float bv = (r == 0) ? ps.b[og + j] : 0.f;
        acc[j * 4] = bv; acc[j * 4 + 1] = bv; acc[j * 4 + 2] = bv; acc[j * 4 + 3] = bv;
    }
    const int base = r * 72;
    if (isbf) proj_body<bf16>((const bf16*)ps.src + (size_t)ps.clip * 144 * NPIX, pix0, og, base, ps.w, acc);
    else      proj_body<float>((const float*)ps.src + (size_t)ps.clip * 144 * NPIX, pix0, og, base, ps.w, acc);
    if (r == 1) {
#pragma unroll
        for (int j = 0; j < 32; ++j) red[lane][j] = acc[j];
    }
    __syncthreads();
    if (r == 0) {
#pragma unroll
        for (int j = 0; j < 32; ++j) acc[j] += red[lane][j];
        const int g = og / 24, cj = og % 24;
#pragma unroll
        for (int px = 0; px < 4; ++px) {
            bf16* ob = ps.dst + ((size_t)(ps.clip * 12 + g) * NPIX + pix0 + px) * 24 + cj;
            uint4 u;
            u.x = ((unsigned)f2bu(acc[1 * 4 + px]) << 16) | f2bu(acc[0 * 4 + px]);
            u.y = ((unsigned)f2bu(acc[3 * 4 + px]) << 16) | f2bu(acc[2 * 4 + px]);
            u.z = ((unsigned)f2bu(acc[5 * 4 + px]) << 16) | f2bu(acc[4 * 4 + px]);
            u.w = ((unsigned)f2bu(acc[7 * 4 + px]) << 16) | f2bu(acc[6 * 4 + px]);
            *(uint4*)ob = u;
        }
    }
}

// ---------------- deformable gather + attention, 8-thread teams ----------------
// team bits: b0=ch half, b1=clip, b2=sample half; (t>>3) -> (m, p)
__global__ __launch_bounds__(256) void attn_kernel(
    const bf16* __restrict__ qp, const bf16* __restrict__ kp,
    const bf16* __restrict__ vp, const float* __restrict__ py,
    const float* __restrict__ px, bf16* __restrict__ att)
{
    const int t = blockIdx.x * 256 + threadIdx.x;
    const int ch = t & 1;
    const int clip = (t >> 1) & 1;
    const int sh = (t >> 2) & 1;
    const int pp = t >> 3;
    const int m = pp >> 12;
    const int p = pp & 4095;

    float qv[12];
    {
        const uint2* s = (const uint2*)(qp + (size_t)(m * 4096 + p) * 24 + ch * 12);
#pragma unroll
        for (int c = 0; c < 3; ++c) {
            uint2 u = s[c];
            qv[c * 4 + 0] = __uint_as_float(u.x << 16);
            qv[c * 4 + 1] = __uint_as_float(u.x & 0xFFFF0000u);
            qv[c * 4 + 2] = __uint_as_float(u.y << 16);
            qv[c * 4 + 3] = __uint_as_float(u.y & 0xFFFF0000u);
        }
    }

    const int gidx = clip * 12 + m;
    const bf16* kb = kp + (size_t)gidx * 4096 * 24 + ch * 12;
    const bf16* vb = vp + (size_t)gidx * 4096 * 24 + ch * 12;
    const int sbase = gidx * 9;
    const int a0 = sh ? 5 : 0;
    const int na = sh ? 4 : 5;

    float e[5], fyv[5], fxv[5];
    float mx = -1e30f;
    for (int i = 0; i < na; ++i) {
        const int a = a0 + i;
        const float fy = py[(sbase + a) * NPIX + p];
        const float fx = px[(sbase + a) * NPIX + p];
        fyv[i] = fy; fxv[i] = fx;
        const float y0 = floorf(fy), x0 = floorf(fx);
        const float wy = fy - y0, wx = fx - x0;
        const int iy = (int)y0, ix = (int)x0;
        const float w00 = (1.f - wy) * (1.f - wx), w01 = (1.f - wy) * wx;
        const float w10 = wy * (1.f - wx), w11 = wy * wx;
        float part = 0.f;
        if ((unsigned)iy < 64u) {
            const bf16* rr = kb + (size_t)(iy * 64) * 24;
            if ((unsigned)ix < 64u)       part += w00 * dot12(rr + ix * 24, qv);
            if ((unsigned)(ix + 1) < 64u) part += w01 * dot12(rr + (ix + 1) * 24, qv);
        }
        if ((unsigned)(iy + 1) < 64u) {
            const bf16* rr = kb + (size_t)((iy + 1) * 64) * 24;
            if ((unsigned)ix < 64u)       part += w10 * dot12(rr + ix * 24, qv);
            if ((unsigned)(ix + 1) < 64u) part += w11 * dot12(rr + (ix + 1) * 24, qv);
        }
        float full = part + __shfl_xor(part, 1, 64);
        e[i] = full * 0.20412414523193154f;   // 24^-0.5
        mx = fmaxf(mx, e[i]);
    }
    mx = fmaxf(mx, __shfl_xor(mx, 4, 64));
    mx = fmaxf(mx, __shfl_xor(mx, 2, 64));
    float sum = 0.f;
    for (int i = 0; i < na; ++i) { e[i] = __expf(e[i] - mx); sum += e[i]; }
    sum += __shfl_xor(sum, 4, 64);
    sum += __shfl_xor(sum, 2, 64);
    const float inv = 1.f / sum;

    float ov[12];
#pragma unroll
    for (int j = 0; j < 12; ++j) ov[j] = 0.f;

    for (int i = 0; i < na; ++i) {
        const float wa = e[i] * inv;
        const float fy = fyv[i], fx = fxv[i];
        const float y0 = floorf(fy), x0 = floorf(fx);
        const float wy = fy - y0, wx = fx - x0;
        const int iy = (int)y0, ix = (int)x0;
        if ((unsigned)iy < 64u) {
            const bf16* rr = vb + (size_t)(iy * 64) * 24;
            if ((unsigned)ix < 64u)       acc12(ov, rr + ix * 24, wa * (1.f - wy) * (1.f - wx));
            if ((unsigned)(ix + 1) < 64u) acc12(ov, rr + (ix + 1) * 24, wa * (1.f - wy) * wx);
        }
        if ((unsigned)(iy + 1) < 64u) {
            const bf16* rr = vb + (size_t)((iy + 1) * 64) * 24;
            if ((unsigned)ix < 64u)       acc12(ov, rr + ix * 24, wa * wy * (1.f - wx));
            if ((unsigned)(ix + 1) < 64u) acc12(ov, rr + (ix + 1) * 24, wa * wy * wx);
        }
    }
#pragma unroll
    for (int j = 0; j < 12; ++j) {
        ov[j] += __shfl_xor(ov[j], 4, 64);
        ov[j] += __shfl_xor(ov[j], 2, 64);
    }
    if (clip == 0 && sh == 0) {
#pragma unroll
        for (int j = 0; j < 12; ++j)
            att[(size_t)(m * 24 + ch * 12 + j) * NPIX + p] = __float2bfloat16(ov[j]);
    }
}

// ---------------- generic channel-linear, split-K(2), 4 out x 2 px ----------------
template <typename TI, int CIN, int ACT>
__global__ __launch_bounds__(256) void linear_kernel(
    const TI* __restrict__ in, const float* __restrict__ w,
    const float* __restrict__ b, int cout, float* __restrict__ out)
{
    __shared__ float red[128][8];
    const int tid = threadIdx.x;
    const int lane = tid & 127, r = tid >> 7;
    const int og = blockIdx.y * 4;
    const int pix0 = (blockIdx.x * 128 + lane) * 2;
    float acc[8];
#pragma unroll
    for (int j = 0; j < 4; ++j) {
        float bv = (r == 0) ? b[og + j] : 0.f;
        acc[j * 2] = bv; acc[j * 2 + 1] = bv;
    }
    for (int i = r * (CIN / 2); i < (r + 1) * (CIN / 2); ++i) {
        float2 a = ld2f(in + i * NPIX + pix0);
#pragma unroll
        for (int j = 0; j < 4; ++j) {
            float wv = w[i * cout + og + j];
            acc[j * 2] += a.x * wv; acc[j * 2 + 1] += a.y * wv;
        }
    }
    if (r == 1) {
#pragma unroll
        for (int j = 0; j < 8; ++j) red[lane][j] = acc[j];
    }
    __syncthreads();
    if (r == 0) {
#pragma unroll
        for (int j = 0; j < 4; ++j) {
            float vx = acc[j * 2] + red[lane][j * 2];
            float vy = acc[j * 2 + 1] + red[lane][j * 2 + 1];
            if (ACT == 1) {
                vx = 0.5f * vx * (1.f + erff(vx * 0.70710678118654752f));
                vy = 0.5f * vy * (1.f + erff(vy * 0.70710678118654752f));
            }
            *(float2*)(out + (og + j) * NPIX + pix0) = make_float2(vx, vy);
        }
    }
}

// ---------------- final: m2 = linear(m1, wm2); out = o + m2, split-K(2), 4 out x 2 px ----------------
__global__ __launch_bounds__(256) void final_kernel(
    const float* __restrict__ m1, const float* __restrict__ w,
    const float* __restrict__ b, const float* __restrict__ o,
    const unsigned short* __restrict__ qraw, void* __restrict__ outv)
{
    __shared__ float red[128][8];
    const int isbf = detect_bf16(qraw);
    const int tid = threadIdx.x;
    const int lane = tid & 127, r = tid >> 7;
    const int og = blockIdx.y * 4;
    const int pix0 = (blockIdx.x * 128 + lane) * 2;
    float acc[8];
#pragma unroll
    for (int j = 0; j < 4; ++j) {
        float bv = (r == 0) ? b[og + j] : 0.f;
        acc[j * 2] = bv; acc[j * 2 + 1] = bv;
    }
    for (int i = r * 144; i < r * 144 + 144; ++i) {
        float2 a = *(const float2*)(m1 + i * NPIX + pix0);
#pragma unroll
        for (int j = 0; j < 4; ++j) {
            float wv = w[i * 144 + og + j];
            acc[j * 2] += a.x * wv; acc[j * 2 + 1] += a.y * wv;
        }
    }
    if (r == 1) {
#pragma unroll
        for (int j = 0; j < 8; ++j) red[lane][j] = acc[j];
    }
    __syncthreads();
    if (r == 0) {
        if (isbf) {
            bf16* out = (bf16*)outv;
#pragma unroll
            for (int j = 0; j < 4; ++j) {
                float2 ov = *(const float2*)(o + (og + j) * NPIX + pix0);
                float vx = acc[j * 2] + red[lane][j * 2] + ov.x;
                float vy = acc[j * 2 + 1] + red[lane][j * 2 + 1] + ov.y;
                unsigned u = ((unsigned)f2bu(vy) << 16) | f2bu(vx);
                *(unsigned*)(out + (og + j) * NPIX + pix0) = u;
            }
        } else {
            float* out = (float*)outv;
#pragma unroll
            for (int j = 0; j < 4; ++j) {
                float2 ov = *(const float2*)(o + (og + j) * NPIX + pix0);
                *(float2*)(out + (og + j) * NPIX + pix0) =
                    make_float2(acc[j * 2] + red[lane][j * 2] + ov.x,
                                acc[j * 2 + 1] + red[lane][j * 2 + 1] + ov.y);
            }
        }
    }
}

// ---------------- diagnostic ----------------
__global__ void diag_kernel(float* __restrict__ out, int n, float v)
{
    int i = blockIdx.x * 256 + threadIdx.x;
    if (i < n) out[i] = (i == 0 ? v : 0.f);
}

extern "C" void kernel_launch(void* const* d_in, const int* in_sizes, int n_in,
                              void* d_out, int out_size, void* d_ws, size_t ws_size,
                              hipStream_t stream)
{
    const size_t REQUIRED = 23115776;
    if (ws_size < REQUIRED) {
        float code = 1000.0f + (float)(ws_size >> 20);
        diag_kernel<<<dim3((out_size + 255) / 256), 256, 0, stream>>>((float*)d_out, out_size, code);
        return;
    }

    char* base = (char*)d_ws;
    float* cw    = (float*)(base + 64);
    float* py    = (float*)(base + 1882112);
    float* px    = (float*)(base + 5421056);
    bf16*  qp    = (bf16*) (base + 8960000);
    bf16*  kp    = (bf16*) (base + 11319296);
    bf16*  vp    = (bf16*) (base + 16037888);
    bf16*  att   = (bf16*) (base + 20756480);
    float* xA    = (float*)(base + 20756480);   // alias att (dead before attn)
    float* xB    = (float*)(base + 21805056);
    float* o     = (float*)(base + 8960000);    // alias qp (dead after attn)
    float* m1    = (float*)(base + 11319296);   // alias kp (dead after attn)

    const int OF_WO1 = 0,      OF_BO1 = 27904,  OF_WO2 = 27968,  OF_BO2 = 64832;
    const int OF_WO3 = 64896,  OF_BO3 = 101760, OF_WO4 = 101824, OF_BO4 = 138688;
    const int OF_WO5 = 138752, OF_BO5 = 175616, OF_WO6 = 175680, OF_BO6 = 203328;
    const int OF_WQ  = 203760, OF_BQ  = 245232, OF_WK  = 245520, OF_BK  = 286992;
    const int OF_WV  = 287280, OF_BV  = 328752, OF_WP  = 329040, OF_BP  = 370512;
    const int OF_WM1 = 370656, OF_BM1 = 412128, OF_WM2 = 412416, OF_BM2 = 453888;
    const int OF_FL0 = 454032, OF_FL1 = 462224;

    const unsigned short* qraw = (const unsigned short*)d_in[0];

    CArgs ca;
    const int srcidx[26] = {7,8,9,10,11,12,13,14,15,16,17,18,19,20,21,22,23,24,25,26,27,28,29,30,5,6};
    const int dsto[26]   = {OF_WO1,OF_BO1,OF_WO2,OF_BO2,OF_WO3,OF_BO3,OF_WO4,OF_BO4,OF_WO5,OF_BO5,
                            OF_WO6,OF_BO6,OF_WQ,OF_BQ,OF_WK,OF_BK,OF_WV,OF_BV,OF_WP,OF_BP,
                            OF_WM1,OF_BM1,OF_WM2,OF_BM2,OF_FL0,OF_FL1};
    for (int i = 0; i < 26; ++i) {
        ca.src[i] = d_in[srcidx[i]];
        ca.dstoff[i] = dsto[i];
        ca.n[i] = in_sizes[srcidx[i]];
    }
    convert_kernel<<<dim3(8, 26), 256, 0, stream>>>(ca, qraw, cw);

    conv1_kernel<<<dim3(16, 32), 256, 0, stream>>>(d_in[0], d_in[3], d_in[4],
                                                   cw + OF_FL0, cw + OF_FL1,
                                                   cw + OF_WO1, cw + OF_BO1, xA);
    conv3_kernel<<<dim3(16, 32), 256, 0, stream>>>(xA, cw + OF_WO2, cw + OF_BO2, xB);
    conv3_kernel<<<dim3(16, 32), 256, 0, stream>>>(xB, cw + OF_WO3, cw + OF_BO3, xA);
    conv3_kernel<<<dim3(16, 32), 256, 0, stream>>>(xA, cw + OF_WO4, cw + OF_BO4, xB);
    conv3_kernel<<<dim3(16, 32), 256, 0, stream>>>(xB, cw + OF_WO5, cw + OF_BO5, xA);
    conv6_off_kernel<<<dim3(16, 54), 256, 0, stream>>>(xA, cw + OF_WO6, cw + OF_BO6,
                                                       cw + OF_FL0, py, px);

    PArgs pa;
    pa.s[0] = { d_in[0], cw + OF_WQ, cw + OF_BQ, qp, 0 };
    pa.s[1] = { d_in[1], cw + OF_WK, cw + OF_BK, kp, 0 };
    pa.s[2] = { d_in[1], cw + OF_WK, cw + OF_BK, kp, 1 };
    pa.s[3] = { d_in[2], cw + OF_WV, cw + OF_BV, vp, 0 };
    pa.s[4] = { d_in[2], cw + OF_WV, cw + OF_BV, vp, 1 };
    proj_kernel<<<dim3(8, 36, 5), 256, 0, stream>>>(pa, qraw);

    attn_kernel<<<dim3(1536), 256, 0, stream>>>(qp, kp, vp, py, px, att);

    linear_kernel<bf16, 288, 0><<<dim3(16, 36), 256, 0, stream>>>(att, cw + OF_WP, cw + OF_BP, 144, o);
    linear_kernel<float, 144, 1><<<dim3(16, 72), 256, 0, stream>>>(o, cw + OF_WM1, cw + OF_BM1, 288, m1);
    final_kernel<<<dim3(16, 36), 256, 0, stream>>>(m1, cw + OF_WM2, cw + OF_BM2, o, qraw, d_out);
}

// Round 8
// 346.384 us; speedup vs baseline: 1.3128x; 1.3128x over previous
//
#include <hip/hip_runtime.h>
#include <hip/hip_bf16.h>
#include <math.h>

typedef __hip_bfloat16 bf16;
typedef __attribute__((ext_vector_type(8))) short bf16x8v;   // 8 bf16 in 4 VGPRs
typedef __attribute__((ext_vector_type(4))) float f32x4v;

#define NPIX 4096

// ---------------- workspace layout (bytes). Peak == 23,592,960 (proven ws lower bound) ----
// cw fp32 small tensors   @ 64        .. 1,881,728   (clobbered by ATT at attn time)
// wbf bf16 weights        @ 1,881,728 .. 2,510,464   (conv1w, conv3w x4, wq, wk, wv)
// QP bf16 [12][4096][24]  @ 2,786,944 .. 5,146,240
// KP bf16 [24][4096][24]  @ 5,146,240 .. 9,864,832
// VP bf16 [24][4096][24]  @ 9,864,832 .. 14,583,424
// X  bf16 [4096][160] x5  @ 14,583,424.. 21,137,024  (staging for proj; dead after proj)
// X1 bf16 [4096][448]     @ 14,583,424 (dead after conv1)
// B3 bf16 [4096][576]     @ 14,583,424.. 19,302,016  (im2col, reused x4)
// Y0/Y1 bf16 [4096][64]   @ 19,302,016 / 19,826,304
// YF bf16 [4096][64]      @ 21,661,312.. 22,185,600
// PY/PX fp32 [216][4096]  @ 14,583,424 / 18,122,368  (after convs; dead after attn)
// ATT bf16 [4096][288]    @ 64        .. 2,359,360   (over dead cw/wbf; < QP ✓)
// OPM bf16 [4096][160]    @ 14,583,424; O32 fp32 [4096][144] @ 15,894,144
// M1 bf16 [4096][288]     @ 18,253,440.. 20,612,736
// SURV (post-attn weights)@ 23,314,176.. 23,592,960 (bp,bm1,bm2 fp32 + wp,wm1,wm2 bf16)

__device__ __forceinline__ float b2f(bf16 v) { return __bfloat162float(v); }
__device__ __forceinline__ unsigned short f2bu(float f) {
    bf16 h = __float2bfloat16(f);
    return *(unsigned short*)&h;
}
__device__ __forceinline__ int detect_bf16(const unsigned short* __restrict__ qraw) {
    int lane = threadIdx.x & 63;
    unsigned short u = qraw[lane * 2];
    int e = (u >> 7) & 0xFF;
    unsigned long long ball = __ballot(e >= 100 && e <= 135);
    return __popcll(ball) > 32;
}

// ---------------- convert 26 small tensors to fp32 (cw) ----------------
struct CArgs { const void* src[26]; int dstoff[26]; int n[26]; };

__global__ void convert_kernel(CArgs a, const unsigned short* __restrict__ qraw,
                               float* __restrict__ cw)
{
    const int isbf = detect_bf16(qraw);
    const int t = blockIdx.y;
    const int n = a.n[t];
    float* d = cw + a.dstoff[t];
    if (isbf) {
        const bf16* s = (const bf16*)a.src[t];
        for (int i = blockIdx.x * 256 + threadIdx.x; i < n; i += 256 * gridDim.x) d[i] = b2f(s[i]);
    } else {
        const float* s = (const float*)a.src[t];
        for (int i = blockIdx.x * 256 + threadIdx.x; i < n; i += 256 * gridDim.x) d[i] = s[i];
    }
}

// ---------------- prepack weights to bf16 [Mp][Kp] (+ survivor biases) ----------------
struct PPJob { int dstS; int Mp, Kp, kr, mr, srcof, sstride, kind; };
struct PPArgs { PPJob j[11]; };

__global__ void prepack_kernel(PPArgs pa, const float* __restrict__ cw, short* __restrict__ wsS,
                               float* __restrict__ wsF)
{
    const int y = blockIdx.y;
    if (y < 11) {
        PPJob J = pa.j[y];
        const int tot = J.Mp * J.Kp;
        for (int e = blockIdx.x * 256 + threadIdx.x; e < tot; e += 256 * gridDim.x) {
            int m = e / J.Kp, k = e - m * J.Kp;
            float v = 0.f;
            if (J.kind == 0) { if (k < J.kr) v = cw[J.srcof + m * J.sstride + k]; }
            else             { if (k < J.kr && m < J.mr) v = cw[J.srcof + k * J.sstride + m]; }
            wsS[J.dstS + e] = (short)f2bu(v);
        }
    } else {
        // biases -> survivor block: bp@5828544, bm1@5828688, bm2@5828976 (float idx)
        const int OF_BP = 370512, OF_BM1 = 412128, OF_BM2 = 453888;
        for (int e = blockIdx.x * 256 + threadIdx.x; e < 576; e += 256 * gridDim.x) {
            if (e < 144)      wsF[5828544 + e] = cw[OF_BP + e];
            else if (e < 432) wsF[5828688 + e - 144] = cw[OF_BM1 + e - 144];
            else              wsF[5828976 + e - 432] = cw[OF_BM2 + e - 432];
        }
    }
}

// ---------------- stage q/k/v -> pixel-major bf16 [4096][160] (pad 144..159 = 0) ---------
__global__ void stage_pm_kernel(const void* __restrict__ s0, const void* __restrict__ s1,
                                const void* __restrict__ s2, const unsigned short* __restrict__ qraw,
                                short* __restrict__ xbase)
{
    const int isbf = detect_bf16(qraw);
    const int z = blockIdx.z;
    const int p = blockIdx.x * 256 + threadIdx.x;
    const int half = blockIdx.y;
    const void* srcs[5] = { s0, s1, s1, s2, s2 };
    const int clips[5] = { 0, 0, 1, 0, 1 };
    const size_t co = (size_t)clips[z] * 144 * NPIX;
    short* row = xbase + (size_t)z * 655360 + (size_t)p * 160;
    for (int c0 = half * 72; c0 < half * 72 + 72; c0 += 8) {
        unsigned short h[8];
        if (isbf) {
            const bf16* s = (const bf16*)srcs[z] + co;
#pragma unroll
            for (int i = 0; i < 8; ++i) h[i] = f2bu(b2f(s[(size_t)(c0 + i) * NPIX + p]));
        } else {
            const float* s = (const float*)srcs[z] + co;
#pragma unroll
            for (int i = 0; i < 8; ++i) h[i] = f2bu(s[(size_t)(c0 + i) * NPIX + p]);
        }
        uint4 u;
        u.x = (unsigned)h[0] | ((unsigned)h[1] << 16);
        u.y = (unsigned)h[2] | ((unsigned)h[3] << 16);
        u.z = (unsigned)h[4] | ((unsigned)h[5] << 16);
        u.w = (unsigned)h[6] | ((unsigned)h[7] << 16);
        *(uint4*)(row + c0) = u;
    }
    if (half == 1) {
        uint4 zz; zz.x = zz.y = zz.z = zz.w = 0u;
        *(uint4*)(row + 144) = zz;
        *(uint4*)(row + 152) = zz;
    }
}

// ---------------- stage conv1 input X1 [4096][448] (concat q,vpw0,vpw1,flows, pad) -------
__global__ void stage_x1_kernel(const void* __restrict__ q, const void* __restrict__ v0,
                                const void* __restrict__ v1, const float* __restrict__ cw,
                                const unsigned short* __restrict__ qraw, short* __restrict__ x1)
{
    const int isbf = detect_bf16(qraw);
    const int p = blockIdx.x * 256 + threadIdx.x;
    const int sec = blockIdx.y;
    short* row = x1 + (size_t)p * 448;
    if (sec < 3) {
        const void* srcs[3] = { q, v0, v1 };
        const int cbase = sec * 144;
        for (int c0 = 0; c0 < 144; c0 += 8) {
            unsigned short h[8];
            if (isbf) {
                const bf16* s = (const bf16*)srcs[sec];
#pragma unroll
                for (int i = 0; i < 8; ++i) h[i] = f2bu(b2f(s[(size_t)(c0 + i) * NPIX + p]));
            } else {
                const float* s = (const float*)srcs[sec];
#pragma unroll
                for (int i = 0; i < 8; ++i) h[i] = f2bu(s[(size_t)(c0 + i) * NPIX + p]);
            }
            uint4 u;
            u.x = (unsigned)h[0] | ((unsigned)h[1] << 16);
            u.y = (unsigned)h[2] | ((unsigned)h[3] << 16);
            u.z = (unsigned)h[4] | ((unsigned)h[5] << 16);
            u.w = (unsigned)h[6] | ((unsigned)h[7] << 16);
            *(uint4*)(row + cbase + c0) = u;
        }
    } else {
        const int OF_FL0 = 454032, OF_FL1 = 462224;
        unsigned short h[4];
        h[0] = f2bu(cw[OF_FL0 + p]);          // flow0 ch0
        h[1] = f2bu(cw[OF_FL0 + NPIX + p]);   // flow0 ch1
        h[2] = f2bu(cw[OF_FL1 + p]);
        h[3] = f2bu(cw[OF_FL1 + NPIX + p]);
        uint4 u;
        u.x = (unsigned)h[0] | ((unsigned)h[1] << 16);
        u.y = (unsigned)h[2] | ((unsigned)h[3] << 16);
        u.z = 0u; u.w = 0u;
        *(uint4*)(row + 432) = u;
        uint4 zz; zz.x = zz.y = zz.z = zz.w = 0u;
        *(uint4*)(row + 440) = zz;
    }
}

// ---------------- MFMA GEMM: D[M][4096] = A[Mp][Kp] * B(pixel-major [4096][Kp]) ----------
struct GemmDesc {
    const short* A; const short* B; const float* bias;
    void* dst; void* dst2; const unsigned short* qraw;
    int Mp, Kp, Mreal, mode, gofs;
};
struct GemmDesc5 { GemmDesc d[5]; };

// modes: 0 = lrelu -> bf16 dst[p*Mp + m]
//        1 = proj  -> bf16 dst[((m/24+gofs)*4096 + p)*24 + m%24]
//        3 = wp    -> bf16 dst[p*160+m] ; fp32 dst2[p*144+m] (m<144)
//        4 = gelu  -> bf16 dst[p*Mp + m]
//        5 = wm2   -> +dst2 residual, store d_out [m*4096+p] (dtype by qraw)
template <int TM, int TN>
__global__ __launch_bounds__(256) void gemm_kernel(GemmDesc5 gd)
{
    const GemmDesc d = gd.d[blockIdx.z];
    const int wid = blockIdx.x * 4 + (threadIdx.x >> 6);
    const int lane = threadIdx.x & 63;
    const int tiles_m = d.Mp / (16 * TM);
    const int m0 = (wid % tiles_m) * (16 * TM);
    const int p0 = (wid / tiles_m) * (16 * TN);
    const int ar = lane & 15;
    const int kq = (lane >> 4) * 8;

    f32x4v acc[TM][TN];
#pragma unroll
    for (int i = 0; i < TM; ++i)
#pragma unroll
        for (int j = 0; j < TN; ++j) acc[i][j] = (f32x4v){0.f, 0.f, 0.f, 0.f};

    for (int k0 = 0; k0 < d.Kp; k0 += 32) {
        bf16x8v a[TM], b[TN];
#pragma unroll
        for (int i = 0; i < TM; ++i)
            a[i] = *(const bf16x8v*)(d.A + (size_t)(m0 + i * 16 + ar) * d.Kp + k0 + kq);
#pragma unroll
        for (int j = 0; j < TN; ++j)
            b[j] = *(const bf16x8v*)(d.B + (size_t)(p0 + j * 16 + ar) * d.Kp + k0 + kq);
#pragma unroll
        for (int i = 0; i < TM; ++i)
#pragma unroll
            for (int j = 0; j < TN; ++j)
                acc[i][j] = __builtin_amdgcn_mfma_f32_16x16x32_bf16(a[i], b[j], acc[i][j], 0, 0, 0);
    }

    const int isbf = (d.mode == 5) ? detect_bf16(d.qraw) : 0;
#pragma unroll
    for (int i = 0; i < TM; ++i) {
#pragma unroll
        for (int j = 0; j < TN; ++j) {
            const int pcol = p0 + j * 16 + (lane & 15);
#pragma unroll
            for (int r = 0; r < 4; ++r) {
                const int m = m0 + i * 16 + (lane >> 4) * 4 + r;
                float v = acc[i][j][r];
                if (m < d.Mreal) v += d.bias[m];
                if (d.mode == 0) {
                    v = (v >= 0.f) ? v : 0.1f * v;
                    ((unsigned short*)d.dst)[(size_t)pcol * d.Mp + m] = f2bu(v);
                } else if (d.mode == 1) {
                    int g = m / 24 + d.gofs;
                    ((unsigned short*)d.dst)[((size_t)g * NPIX + pcol) * 24 + (m % 24)] = f2bu(v);
                } else if (d.mode == 3) {
                    ((unsigned short*)d.dst)[(size_t)pcol * 160 + m] = f2bu(v);
                    if (m < 144) ((float*)d.dst2)[(size_t)pcol * 144 + m] = v;
                } else if (d.mode == 4) {
                    v = 0.5f * v * (1.f + erff(v * 0.70710678118654752f));
                    ((unsigned short*)d.dst)[(size_t)pcol * d.Mp + m] = f2bu(v);
                } else { // 5
                    if (m < 144) {
                        v += ((float*)d.dst2)[(size_t)pcol * 144 + m];
                        if (isbf) ((unsigned short*)d.dst)[(size_t)m * NPIX + pcol] = f2bu(v);
                        else      ((float*)d.dst)[(size_t)m * NPIX + pcol] = v;
                    }
                }
            }
        }
    }
}

// ---------------- im2col: Y [4096][64] bf16 -> B3 [4096][576] bf16 -----------------------
__device__ __forceinline__ unsigned short hw_get(const uint4& v, int idx) {
    unsigned w = (idx < 2) ? v.x : (idx < 4) ? v.y : (idx < 6) ? v.z : v.w;
    return (idx & 1) ? (unsigned short)(w >> 16) : (unsigned short)(w & 0xffff);
}

__global__ __launch_bounds__(256) void im2col_kernel(const short* __restrict__ Y,
                                                     short* __restrict__ B3)
{
    const int t = blockIdx.x * 256 + threadIdx.x;   // 4096 px * 8 cgroups
    const int p = t >> 3;
    const int c0 = (t & 7) * 8;
    const int y = p >> 6, x = p & 63;
    uint4 v[9];
#pragma unroll
    for (int tap = 0; tap < 9; ++tap) {
        int yy = y + tap / 3 - 1, xx = x + tap % 3 - 1;
        int ok = ((unsigned)yy < 64u) & ((unsigned)xx < 64u);
        int idx = ok ? (yy * 64 + xx) : p;
        uint4 u = *(const uint4*)(Y + (size_t)idx * 64 + c0);
        if (!ok) { u.x = 0u; u.y = 0u; u.z = 0u; u.w = 0u; }
        v[tap] = u;
    }
    short* orow = B3 + (size_t)p * 576 + c0 * 9;    // 72 contiguous bf16 = 9 uint4
#pragma unroll
    for (int w = 0; w < 9; ++w) {
        unsigned short h[8];
#pragma unroll
        for (int s = 0; s < 8; ++s) {
            int e = w * 8 + s;          // e = c*9 + tap
            h[s] = hw_get(v[e % 9], e / 9);
        }
        uint4 u;
        u.x = (unsigned)h[0] | ((unsigned)h[1] << 16);
        u.y = (unsigned)h[2] | ((unsigned)h[3] << 16);
        u.z = (unsigned)h[4] | ((unsigned)h[5] << 16);
        u.w = (unsigned)h[6] | ((unsigned)h[7] << 16);
        ((uint4*)orow)[w] = u;
    }
}

// ---------------- conv6: YF [4096][64] bf16 -> py/px, 16 outs/thread ---------------------
__global__ __launch_bounds__(256) void conv6_kernel(const short* __restrict__ YF,
                                                    const float* __restrict__ cw,
                                                    float* __restrict__ py, float* __restrict__ px)
{
    const int OF_WO6 = 175680, OF_BO6 = 203328, OF_FL0 = 454032;
    const int p = blockIdx.x * 256 + threadIdx.x;
    const int o0 = blockIdx.y * 16;
    float xv[64];
    const uint4* yrow = (const uint4*)(YF + (size_t)p * 64);
#pragma unroll
    for (int c = 0; c < 8; ++c) {
        uint4 u = yrow[c];
        xv[c * 8 + 0] = __uint_as_float(u.x << 16);
        xv[c * 8 + 1] = __uint_as_float(u.x & 0xFFFF0000u);
        xv[c * 8 + 2] = __uint_as_float(u.y << 16);
        xv[c * 8 + 3] = __uint_as_float(u.y & 0xFFFF0000u);
        xv[c * 8 + 4] = __uint_as_float(u.z << 16);
        xv[c * 8 + 5] = __uint_as_float(u.z & 0xFFFF0000u);
        xv[c * 8 + 6] = __uint_as_float(u.w << 16);
        xv[c * 8 + 7] = __uint_as_float(u.w & 0xFFFF0000u);
    }
    float acc[16];
#pragma unroll
    for (int j = 0; j < 16; ++j) acc[j] = cw[OF_BO6 + o0 + j];
    for (int i = 0; i < 64; ++i) {
        float a = xv[i];
#pragma unroll
        for (int j = 0; j < 16; ++j) acc[j] += a * cw[OF_WO6 + (o0 + j) * 64 + i];
    }
    const float f_y = cw[OF_FL0 + NPIX + p];
    const float f_x = cw[OF_FL0 + p];
    const float yf = (float)(p >> 6), xf = (float)(p & 63);
#pragma unroll
    for (int j = 0; j < 16; ++j) {
        int o = o0 + j;
        float val = 10.f * tanhf(acc[j]);
        int s = o >> 1;
        int a_idx = s % 9;
        if ((o & 1) == 0) py[s * NPIX + p] = val + f_y + (float)(a_idx / 3 - 1) + yf;
        else              px[s * NPIX + p] = val + f_x + (float)(a_idx % 3 - 1) + xf;
    }
}

// ---------------- deformable gather + attention, 8-thread teams -> att pixel-major -------
__device__ __forceinline__ float dot12(const bf16* __restrict__ row, const float* qv) {
    const uint2* s = (const uint2*)row;
    float d = 0.f;
#pragma unroll
    for (int c = 0; c < 3; ++c) {
        uint2 u = s[c];
        d += qv[c * 4 + 0] * __uint_as_float(u.x << 16);
        d += qv[c * 4 + 1] * __uint_as_float(u.x & 0xFFFF0000u);
        d += qv[c * 4 + 2] * __uint_as_float(u.y << 16);
        d += qv[c * 4 + 3] * __uint_as_float(u.y & 0xFFFF0000u);
    }
    return d;
}
__device__ __forceinline__ void acc12(float* ov, const bf16* __restrict__ row, float f) {
    const uint2* s = (const uint2*)row;
#pragma unroll
    for (int c = 0; c < 3; ++c) {
        uint2 u = s[c];
        ov[c * 4 + 0] += f * __uint_as_float(u.x << 16);
        ov[c * 4 + 1] += f * __uint_as_float(u.x & 0xFFFF0000u);
        ov[c * 4 + 2] += f * __uint_as_float(u.y << 16);
        ov[c * 4 + 3] += f * __uint_as_float(u.y & 0xFFFF0000u);
    }
}

__global__ __launch_bounds__(256) void attn_kernel(
    const bf16* __restrict__ qp, const bf16* __restrict__ kp,
    const bf16* __restrict__ vp, const float* __restrict__ py,
    const float* __restrict__ px, unsigned short* __restrict__ att)
{
    const int t = blockIdx.x * 256 + threadIdx.x;
    const int ch = t & 1;
    const int clip = (t >> 1) & 1;
    const int sh = (t >> 2) & 1;
    const int pp = t >> 3;
    const int m = pp >> 12;
    const int p = pp & 4095;

    float qv[12];
    {
        const uint2* s = (const uint2*)(qp + (size_t)(m * 4096 + p) * 24 + ch * 12);
#pragma unroll
        for (int c = 0; c < 3; ++c) {
            uint2 u = s[c];
            qv[c * 4 + 0] = __uint_as_float(u.x << 16);
            qv[c * 4 + 1] = __uint_as_float(u.x & 0xFFFF0000u);
            qv[c * 4 + 2] = __uint_as_float(u.y << 16);
            qv[c * 4 + 3] = __uint_as_float(u.y & 0xFFFF0000u);
        }
    }

    const int gidx = clip * 12 + m;
    const bf16* kb = kp + (size_t)gidx * 4096 * 24 + ch * 12;
    const bf16* vb = vp + (size_t)gidx * 4096 * 24 + ch * 12;
    const int sbase = gidx * 9;
    const int a0 = sh ? 5 : 0;
    const int na = sh ? 4 : 5;

    float e[5], fyv[5], fxv[5];
    float mx = -1e30f;
    for (int i = 0; i < na; ++i) {
        const int a = a0 + i;
        const float fy = py[(sbase + a) * NPIX + p];
        const float fx = px[(sbase + a) * NPIX + p];
        fyv[i] = fy; fxv[i] = fx;
        const float y0 = floorf(fy), x0 = floorf(fx);
        const float wy = fy - y0, wx = fx - x0;
        const int iy = (int)y0, ix = (int)x0;
        const float w00 = (1.f - wy) * (1.f - wx), w01 = (1.f - wy) * wx;
        const float w10 = wy * (1.f - wx), w11 = wy * wx;
        float part = 0.f;
        if ((unsigned)iy < 64u) {
            const bf16* rr = kb + (size_t)(iy * 64) * 24;
            if ((unsigned)ix < 64u)       part += w00 * dot12(rr + ix * 24, qv);
            if ((unsigned)(ix + 1) < 64u) part += w01 * dot12(rr + (ix + 1) * 24, qv);
        }
        if ((unsigned)(iy + 1) < 64u) {
            const bf16* rr = kb + (size_t)((iy + 1) * 64) * 24;
            if ((unsigned)ix < 64u)       part += w10 * dot12(rr + ix * 24, qv);
            if ((unsigned)(ix + 1) < 64u) part += w11 * dot12(rr + (ix + 1) * 24, qv);
        }
        float full = part + __shfl_xor(part, 1, 64);
        e[i] = full * 0.20412414523193154f;
        mx = fmaxf(mx, e[i]);
    }
    mx = fmaxf(mx, __shfl_xor(mx, 4, 64));
    mx = fmaxf(mx, __shfl_xor(mx, 2, 64));
    float sum = 0.f;
    for (int i = 0; i < na; ++i) { e[i] = __expf(e[i] - mx); sum += e[i]; }
    sum += __shfl_xor(sum, 4, 64);
    sum += __shfl_xor(sum, 2, 64);
    const float inv = 1.f / sum;

    float ov[12];
#pragma unroll
    for (int j = 0; j < 12; ++j) ov[j] = 0.f;

    for (int i = 0; i < na; ++i) {
        const float wa = e[i] * inv;
        const float fy = fyv[i], fx = fxv[i];
        const float y0 = floorf(fy), x0 = floorf(fx);
        const float wy = fy - y0, wx = fx - x0;
        const int iy = (int)y0, ix = (int)x0;
        if ((unsigned)iy < 64u) {
            const bf16* rr = vb + (size_t)(iy * 64) * 24;
            if ((unsigned)ix < 64u)       acc12(ov, rr + ix * 24, wa * (1.f - wy) * (1.f - wx));
            if ((unsigned)(ix + 1) < 64u) acc12(ov, rr + (ix + 1) * 24, wa * (1.f - wy) * wx);
        }
        if ((unsigned)(iy + 1) < 64u) {
            const bf16* rr = vb + (size_t)((iy + 1) * 64) * 24;
            if ((unsigned)ix < 64u)       acc12(ov, rr + ix * 24, wa * wy * (1.f - wx));
            if ((unsigned)(ix + 1) < 64u) acc12(ov, rr + (ix + 1) * 24, wa * wy * wx);
        }
    }
#pragma unroll
    for (int j = 0; j < 12; ++j) {
        ov[j] += __shfl_xor(ov[j], 4, 64);
        ov[j] += __shfl_xor(ov[j], 2, 64);
    }
    if (clip == 0 && sh == 0) {
        unsigned short* ab = att + (size_t)p * 288 + m * 24 + ch * 12;
#pragma unroll
        for (int c = 0; c < 3; ++c) {
            uint2 u;
            u.x = (unsigned)f2bu(ov[c * 4 + 0]) | ((unsigned)f2bu(ov[c * 4 + 1]) << 16);
            u.y = (unsigned)f2bu(ov[c * 4 + 2]) | ((unsigned)f2bu(ov[c * 4 + 3]) << 16);
            ((uint2*)ab)[c] = u;
        }
    }
}

// ---------------- diagnostic ----------------
__global__ void diag_kernel(float* __restrict__ out, int n, float v)
{
    int i = blockIdx.x * 256 + threadIdx.x;
    if (i < n) out[i] = (i == 0 ? v : 0.f);
}

extern "C" void kernel_launch(void* const* d_in, const int* in_sizes, int n_in,
                              void* d_out, int out_size, void* d_ws, size_t ws_size,
                              hipStream_t stream)
{
    const size_t REQUIRED = 23592960;
    if (ws_size < REQUIRED) {
        float code = 1000.0f + (float)(ws_size >> 20);
        diag_kernel<<<dim3((out_size + 255) / 256), 256, 0, stream>>>((float*)d_out, out_size, code);
        return;
    }

    char* W = (char*)d_ws;
    short* wsS = (short*)W;
    float* wsF = (float*)W;
    float* cw = (float*)(W + 64);

    // cw element offsets (within cw)
    const int OF_WO1 = 0,      OF_BO1 = 27904,  OF_WO2 = 27968,  OF_BO2 = 64832;
    const int OF_WO3 = 64896,  OF_BO3 = 101760, OF_WO4 = 101824, OF_BO4 = 138688;
    const int OF_WO5 = 138752, OF_BO5 = 175616, OF_WO6 = 175680, OF_BO6 = 203328;
    const int OF_WQ  = 203760, OF_BQ  = 245232, OF_WK  = 245520, OF_BK  = 286992;
    const int OF_WV  = 287280, OF_BV  = 328752, OF_WP  = 329040, OF_BP  = 370512;
    const int OF_WM1 = 370656, OF_BM1 = 412128, OF_WM2 = 412416, OF_BM2 = 453888;
    const int OF_FL0 = 454032, OF_FL1 = 462224;
    (void)OF_BO6; (void)OF_FL1;

    // short-index bases
    short* conv1w = wsS + 940864;
    short* conv3w0 = wsS + 969536;
    short* wqb = wsS + 1116992, *wkb = wsS + 1163072, *wvb = wsS + 1209152;
    short* wpS = wsS + 11658240, *wm1S = wsS + 11704320, *wm2S = wsS + 11750400;
    float* bpS = wsF + 5828544, *bm1S = wsF + 5828688, *bm2S = wsF + 5828976;
    bf16* QP = (bf16*)(W + 2786944);
    bf16* KP = (bf16*)(W + 5146240);
    bf16* VP = (bf16*)(W + 9864832);
    short* XS = (short*)(W + 14583424);          // Xq..Xv1 / X1 / B3 / OPM base
    short* X1 = XS;
    short* B3 = XS;
    short* Y0 = (short*)(W + 19302016);
    short* Y1 = (short*)(W + 19826304);
    short* YF = (short*)(W + 21661312);
    float* PY = (float*)(W + 14583424);
    float* PX = (float*)(W + 18122368);
    unsigned short* ATT = (unsigned short*)(W + 64);
    short* OPM = (short*)(W + 14583424);
    float* O32 = (float*)(W + 15894144);
    short* M1 = (short*)(W + 18253440);

    const unsigned short* qraw = (const unsigned short*)d_in[0];

    // 1. convert small tensors to fp32
    CArgs ca;
    const int srcidx[26] = {7,8,9,10,11,12,13,14,15,16,17,18,19,20,21,22,23,24,25,26,27,28,29,30,5,6};
    const int dsto[26]   = {OF_WO1,OF_BO1,OF_WO2,OF_BO2,OF_WO3,OF_BO3,OF_WO4,OF_BO4,OF_WO5,OF_BO5,
                            OF_WO6,203328,OF_WQ,OF_BQ,OF_WK,OF_BK,OF_WV,OF_BV,OF_WP,OF_BP,
                            OF_WM1,OF_BM1,OF_WM2,OF_BM2,OF_FL0,462224};
    for (int i = 0; i < 26; ++i) {
        ca.src[i] = d_in[srcidx[i]];
        ca.dstoff[i] = dsto[i];
        ca.n[i] = in_sizes[srcidx[i]];
    }
    convert_kernel<<<dim3(8, 26), 256, 0, stream>>>(ca, qraw, cw);

    // 2. prepack weights
    PPArgs pp;
    pp.j[0]  = { 940864,  64, 448, 436, 64,  OF_WO1, 436, 0 };
    pp.j[1]  = { 969536,  64, 576, 576, 64,  OF_WO2, 576, 0 };
    pp.j[2]  = { 1006400, 64, 576, 576, 64,  OF_WO3, 576, 0 };
    pp.j[3]  = { 1043264, 64, 576, 576, 64,  OF_WO4, 576, 0 };
    pp.j[4]  = { 1080128, 64, 576, 576, 64,  OF_WO5, 576, 0 };
    pp.j[5]  = { 1116992, 288, 160, 144, 288, OF_WQ, 288, 1 };
    pp.j[6]  = { 1163072, 288, 160, 144, 288, OF_WK, 288, 1 };
    pp.j[7]  = { 1209152, 288, 160, 144, 288, OF_WV, 288, 1 };
    pp.j[8]  = { 11658240, 160, 288, 288, 144, OF_WP, 144, 1 };
    pp.j[9]  = { 11704320, 288, 160, 144, 288, OF_WM1, 288, 1 };
    pp.j[10] = { 11750400, 160, 288, 288, 144, OF_WM2, 144, 1 };
    prepack_kernel<<<dim3(64, 12), 256, 0, stream>>>(pp, cw, wsS, wsF);

    // 3. stage q/k/v pixel-major
    stage_pm_kernel<<<dim3(16, 2, 5), 256, 0, stream>>>(d_in[0], d_in[1], d_in[2], qraw, XS);

    // 4. proj GEMMs (5 slices)
    GemmDesc5 gproj;
    const short* Xz[5] = { XS, XS + 655360, XS + 1310720, XS + 1966080, XS + 2621440 };
    const short* Az[5] = { wqb, wkb, wkb, wvb, wvb };
    const float* Bz[5] = { cw + OF_BQ, cw + OF_BK, cw + OF_BK, cw + OF_BV, cw + OF_BV };
    bf16* Dz[5] = { QP, KP, KP, VP, VP };
    const int Gz[5] = { 0, 0, 12, 0, 12 };
    for (int z = 0; z < 5; ++z)
        gproj.d[z] = { Az[z], Xz[z], Bz[z], Dz[z], nullptr, qraw, 288, 160, 288, 1, Gz[z] };
    gemm_kernel<2, 2><<<dim3(288, 1, 5), 256, 0, stream>>>(gproj);

    // 5. stage X1 (over dead Xq region)
    stage_x1_kernel<<<dim3(16, 4), 256, 0, stream>>>(d_in[0], d_in[3], d_in[4], cw, qraw, X1);

    // 6. conv1 GEMM -> Y0
    GemmDesc5 g1;
    g1.d[0] = { conv1w, X1, cw + OF_BO1, Y0, nullptr, qraw, 64, 448, 64, 0, 0 };
    gemm_kernel<1, 1><<<dim3(256, 1, 1), 256, 0, stream>>>(g1);

    // 7-14. conv3 chain (im2col + GEMM) x4
    const float* cb[4] = { cw + OF_BO2, cw + OF_BO3, cw + OF_BO4, cw + OF_BO5 };
    short* cin[4] = { Y0, Y1, Y0, Y1 };
    short* cout[4] = { Y1, Y0, Y1, YF };
    for (int i = 0; i < 4; ++i) {
        im2col_kernel<<<dim3(128), 256, 0, stream>>>(cin[i], B3);
        GemmDesc5 g3;
        g3.d[0] = { conv3w0 + i * 36864, B3, cb[i], cout[i], nullptr, qraw, 64, 576, 64, 0, 0 };
        gemm_kernel<1, 1><<<dim3(256, 1, 1), 256, 0, stream>>>(g3);
    }

    // 15. conv6 -> py/px
    conv6_kernel<<<dim3(16, 27), 256, 0, stream>>>(YF, cw, PY, PX);

    // 16. attention -> att (pixel-major, clobbers cw/wbf region)
    attn_kernel<<<dim3(1536), 256, 0, stream>>>(QP, KP, VP, PY, PX, ATT);

    // 17. wp GEMM -> o_pm + o32
    GemmDesc5 gwp;
    gwp.d[0] = { wpS, (const short*)ATT, bpS, OPM, O32, qraw, 160, 288, 144, 3, 0 };
    gemm_kernel<2, 2><<<dim3(160, 1, 1), 256, 0, stream>>>(gwp);

    // 18. wm1 GEMM + gelu -> m1
    GemmDesc5 gm1;
    gm1.d[0] = { wm1S, OPM, bm1S, M1, nullptr, qraw, 288, 160, 288, 4, 0 };
    gemm_kernel<2, 2><<<dim3(288, 1, 1), 256, 0, stream>>>(gm1);

    // 19. wm2 GEMM + residual -> d_out
    GemmDesc5 gm2;
    gm2.d[0] = { wm2S, M1, bm2S, d_out, O32, qraw, 160, 288, 144, 5, 0 };
    gemm_kernel<2, 2><<<dim3(160, 1, 1), 256, 0, stream>>>(gm2);
}

// Round 9
// 339.474 us; speedup vs baseline: 1.3395x; 1.0204x over previous
//
#include <hip/hip_runtime.h>
#include <hip/hip_bf16.h>
#include <math.h>

typedef __hip_bfloat16 bf16;
typedef __attribute__((ext_vector_type(8))) short bf16x8v;   // 8 bf16 in 4 VGPRs
typedef __attribute__((ext_vector_type(4))) float f32x4v;

#define NPIX 4096

__device__ __forceinline__ float b2f(bf16 v) { return __bfloat162float(v); }
__device__ __forceinline__ unsigned short f2bu(float f) {
    bf16 h = __float2bfloat16(f);
    return *(unsigned short*)&h;
}
__device__ __forceinline__ int detect_bf16(const unsigned short* __restrict__ qraw) {
    int lane = threadIdx.x & 63;
    unsigned short u = qraw[lane * 2];
    int e = (u >> 7) & 0xFF;
    unsigned long long ball = __ballot(e >= 100 && e <= 135);
    return __popcll(ball) > 32;
}

// ---------------- convert 26 small tensors to fp32 (cw) ----------------
struct CArgs { const void* src[26]; int dstoff[26]; int n[26]; };

__global__ void convert_kernel(CArgs a, const unsigned short* __restrict__ qraw,
                               float* __restrict__ cw)
{
    const int isbf = detect_bf16(qraw);
    const int t = blockIdx.y;
    const int n = a.n[t];
    float* d = cw + a.dstoff[t];
    if (isbf) {
        const bf16* s = (const bf16*)a.src[t];
        for (int i = blockIdx.x * 256 + threadIdx.x; i < n; i += 256 * gridDim.x) d[i] = b2f(s[i]);
    } else {
        const float* s = (const float*)a.src[t];
        for (int i = blockIdx.x * 256 + threadIdx.x; i < n; i += 256 * gridDim.x) d[i] = s[i];
    }
}

// ---------------- prepack weights to bf16 [Mp][Kp] (+ survivor biases) ----------------
struct PPJob { int dstS; int Mp, Kp, kr, mr, srcof, sstride, kind; };
struct PPArgs { PPJob j[11]; };

__global__ void prepack_kernel(PPArgs pa, const float* __restrict__ cw, short* __restrict__ wsS,
                               float* __restrict__ wsF)
{
    const int y = blockIdx.y;
    if (y < 11) {
        PPJob J = pa.j[y];
        const int tot = J.Mp * J.Kp;
        for (int e = blockIdx.x * 256 + threadIdx.x; e < tot; e += 256 * gridDim.x) {
            int m = e / J.Kp, k = e - m * J.Kp;
            float v = 0.f;
            if (J.kind == 0) { if (k < J.kr) v = cw[J.srcof + m * J.sstride + k]; }
            else             { if (k < J.kr && m < J.mr) v = cw[J.srcof + k * J.sstride + m]; }
            wsS[J.dstS + e] = (short)f2bu(v);
        }
    } else {
        const int OF_BP = 370512, OF_BM1 = 412128, OF_BM2 = 453888;
        for (int e = blockIdx.x * 256 + threadIdx.x; e < 576; e += 256 * gridDim.x) {
            if (e < 144)      wsF[5828544 + e] = cw[OF_BP + e];
            else if (e < 432) wsF[5828688 + e - 144] = cw[OF_BM1 + e - 144];
            else              wsF[5828976 + e - 432] = cw[OF_BM2 + e - 432];
        }
    }
}

// ---------------- stage q/k/v -> pixel-major bf16 [4096][160] (pad 144..159 = 0) ---------
__global__ void stage_pm_kernel(const void* __restrict__ s0, const void* __restrict__ s1,
                                const void* __restrict__ s2, const unsigned short* __restrict__ qraw,
                                short* __restrict__ xbase)
{
    const int isbf = detect_bf16(qraw);
    const int z = blockIdx.z;
    const int p = blockIdx.x * 256 + threadIdx.x;
    const int half = blockIdx.y;
    const void* srcs[5] = { s0, s1, s1, s2, s2 };
    const int clips[5] = { 0, 0, 1, 0, 1 };
    const size_t co = (size_t)clips[z] * 144 * NPIX;
    short* row = xbase + (size_t)z * 655360 + (size_t)p * 160;
    for (int c0 = half * 72; c0 < half * 72 + 72; c0 += 8) {
        unsigned short h[8];
        if (isbf) {
            const bf16* s = (const bf16*)srcs[z] + co;
#pragma unroll
            for (int i = 0; i < 8; ++i) h[i] = f2bu(b2f(s[(size_t)(c0 + i) * NPIX + p]));
        } else {
            const float* s = (const float*)srcs[z] + co;
#pragma unroll
            for (int i = 0; i < 8; ++i) h[i] = f2bu(s[(size_t)(c0 + i) * NPIX + p]);
        }
        uint4 u;
        u.x = (unsigned)h[0] | ((unsigned)h[1] << 16);
        u.y = (unsigned)h[2] | ((unsigned)h[3] << 16);
        u.z = (unsigned)h[4] | ((unsigned)h[5] << 16);
        u.w = (unsigned)h[6] | ((unsigned)h[7] << 16);
        *(uint4*)(row + c0) = u;
    }
    if (half == 1) {
        uint4 zz; zz.x = zz.y = zz.z = zz.w = 0u;
        *(uint4*)(row + 144) = zz;
        *(uint4*)(row + 152) = zz;
    }
}

// ---------------- stage conv1 input X1 [4096][448] ----------------
__global__ void stage_x1_kernel(const void* __restrict__ q, const void* __restrict__ v0,
                                const void* __restrict__ v1, const float* __restrict__ cw,
                                const unsigned short* __restrict__ qraw, short* __restrict__ x1)
{
    const int isbf = detect_bf16(qraw);
    const int p = blockIdx.x * 256 + threadIdx.x;
    const int sec = blockIdx.y;
    short* row = x1 + (size_t)p * 448;
    if (sec < 3) {
        const void* srcs[3] = { q, v0, v1 };
        const int cbase = sec * 144;
        for (int c0 = 0; c0 < 144; c0 += 8) {
            unsigned short h[8];
            if (isbf) {
                const bf16* s = (const bf16*)srcs[sec];
#pragma unroll
                for (int i = 0; i < 8; ++i) h[i] = f2bu(b2f(s[(size_t)(c0 + i) * NPIX + p]));
            } else {
                const float* s = (const float*)srcs[sec];
#pragma unroll
                for (int i = 0; i < 8; ++i) h[i] = f2bu(s[(size_t)(c0 + i) * NPIX + p]);
            }
            uint4 u;
            u.x = (unsigned)h[0] | ((unsigned)h[1] << 16);
            u.y = (unsigned)h[2] | ((unsigned)h[3] << 16);
            u.z = (unsigned)h[4] | ((unsigned)h[5] << 16);
            u.w = (unsigned)h[6] | ((unsigned)h[7] << 16);
            *(uint4*)(row + cbase + c0) = u;
        }
    } else {
        const int OF_FL0 = 454032, OF_FL1 = 462224;
        unsigned short h[4];
        h[0] = f2bu(cw[OF_FL0 + p]);
        h[1] = f2bu(cw[OF_FL0 + NPIX + p]);
        h[2] = f2bu(cw[OF_FL1 + p]);
        h[3] = f2bu(cw[OF_FL1 + NPIX + p]);
        uint4 u;
        u.x = (unsigned)h[0] | ((unsigned)h[1] << 16);
        u.y = (unsigned)h[2] | ((unsigned)h[3] << 16);
        u.z = 0u; u.w = 0u;
        *(uint4*)(row + 432) = u;
        uint4 zz; zz.x = zz.y = zz.z = zz.w = 0u;
        *(uint4*)(row + 440) = zz;
    }
}

// ---------------- MFMA GEMM ----------------
struct GemmDesc {
    const short* A; const short* B; const float* bias;
    void* dst; void* dst2; const unsigned short* qraw;
    int Mp, Kp, Mreal, mode, gofs;
};
struct GemmDesc5 { GemmDesc d[5]; };

template <int TM, int TN>
__global__ __launch_bounds__(256) void gemm_kernel(GemmDesc5 gd)
{
    const GemmDesc d = gd.d[blockIdx.z];
    const int wid = blockIdx.x * 4 + (threadIdx.x >> 6);
    const int lane = threadIdx.x & 63;
    const int tiles_m = d.Mp / (16 * TM);
    const int m0 = (wid % tiles_m) * (16 * TM);
    const int p0 = (wid / tiles_m) * (16 * TN);
    const int ar = lane & 15;
    const int kq = (lane >> 4) * 8;

    f32x4v acc[TM][TN];
#pragma unroll
    for (int i = 0; i < TM; ++i)
#pragma unroll
        for (int j = 0; j < TN; ++j) acc[i][j] = (f32x4v){0.f, 0.f, 0.f, 0.f};

    for (int k0 = 0; k0 < d.Kp; k0 += 32) {
        bf16x8v a[TM], b[TN];
#pragma unroll
        for (int i = 0; i < TM; ++i)
            a[i] = *(const bf16x8v*)(d.A + (size_t)(m0 + i * 16 + ar) * d.Kp + k0 + kq);
#pragma unroll
        for (int j = 0; j < TN; ++j)
            b[j] = *(const bf16x8v*)(d.B + (size_t)(p0 + j * 16 + ar) * d.Kp + k0 + kq);
#pragma unroll
        for (int i = 0; i < TM; ++i)
#pragma unroll
            for (int j = 0; j < TN; ++j)
                acc[i][j] = __builtin_amdgcn_mfma_f32_16x16x32_bf16(a[i], b[j], acc[i][j], 0, 0, 0);
    }

    const int isbf = (d.mode == 5) ? detect_bf16(d.qraw) : 0;
#pragma unroll
    for (int i = 0; i < TM; ++i) {
#pragma unroll
        for (int j = 0; j < TN; ++j) {
            const int pcol = p0 + j * 16 + (lane & 15);
#pragma unroll
            for (int r = 0; r < 4; ++r) {
                const int m = m0 + i * 16 + (lane >> 4) * 4 + r;
                float v = acc[i][j][r];
                if (m < d.Mreal) v += d.bias[m];
                if (d.mode == 0) {
                    v = (v >= 0.f) ? v : 0.1f * v;
                    ((unsigned short*)d.dst)[(size_t)pcol * d.Mp + m] = f2bu(v);
                } else if (d.mode == 1) {
                    int g = m / 24 + d.gofs;
                    ((unsigned short*)d.dst)[((size_t)g * NPIX + pcol) * 24 + (m % 24)] = f2bu(v);
                } else if (d.mode == 3) {
                    ((unsigned short*)d.dst)[(size_t)pcol * 160 + m] = f2bu(v);
                    if (m < 144) ((float*)d.dst2)[(size_t)pcol * 144 + m] = v;
                } else if (d.mode == 4) {
                    v = 0.5f * v * (1.f + erff(v * 0.70710678118654752f));
                    ((unsigned short*)d.dst)[(size_t)pcol * d.Mp + m] = f2bu(v);
                } else { // 5
                    if (m < 144) {
                        v += ((float*)d.dst2)[(size_t)pcol * 144 + m];
                        if (isbf) ((unsigned short*)d.dst)[(size_t)m * NPIX + pcol] = f2bu(v);
                        else      ((float*)d.dst)[(size_t)m * NPIX + pcol] = v;
                    }
                }
            }
        }
    }
}

// ---------------- im2col ----------------
__device__ __forceinline__ unsigned short hw_get(const uint4& v, int idx) {
    unsigned w = (idx < 2) ? v.x : (idx < 4) ? v.y : (idx < 6) ? v.z : v.w;
    return (idx & 1) ? (unsigned short)(w >> 16) : (unsigned short)(w & 0xffff);
}

__global__ __launch_bounds__(256) void im2col_kernel(const short* __restrict__ Y,
                                                     short* __restrict__ B3)
{
    const int t = blockIdx.x * 256 + threadIdx.x;
    const int p = t >> 3;
    const int c0 = (t & 7) * 8;
    const int y = p >> 6, x = p & 63;
    uint4 v[9];
#pragma unroll
    for (int tap = 0; tap < 9; ++tap) {
        int yy = y + tap / 3 - 1, xx = x + tap % 3 - 1;
        int ok = ((unsigned)yy < 64u) & ((unsigned)xx < 64u);
        int idx = ok ? (yy * 64 + xx) : p;
        uint4 u = *(const uint4*)(Y + (size_t)idx * 64 + c0);
        if (!ok) { u.x = 0u; u.y = 0u; u.z = 0u; u.w = 0u; }
        v[tap] = u;
    }
    short* orow = B3 + (size_t)p * 576 + c0 * 9;
#pragma unroll
    for (int w = 0; w < 9; ++w) {
        unsigned short h[8];
#pragma unroll
        for (int s = 0; s < 8; ++s) {
            int e = w * 8 + s;
            h[s] = hw_get(v[e % 9], e / 9);
        }
        uint4 u;
        u.x = (unsigned)h[0] | ((unsigned)h[1] << 16);
        u.y = (unsigned)h[2] | ((unsigned)h[3] << 16);
        u.z = (unsigned)h[4] | ((unsigned)h[5] << 16);
        u.w = (unsigned)h[6] | ((unsigned)h[7] << 16);
        ((uint4*)orow)[w] = u;
    }
}

// ---------------- conv6: fully static-unrolled (no scratch) ----------------
__global__ __launch_bounds__(256) void conv6_kernel(const short* __restrict__ YF,
                                                    const float* __restrict__ cw,
                                                    float* __restrict__ py, float* __restrict__ px)
{
    const int OF_WO6 = 175680, OF_BO6 = 203328, OF_FL0 = 454032;
    const int p = blockIdx.x * 256 + threadIdx.x;
    const int o0 = blockIdx.y * 16;
    const uint4* yrow = (const uint4*)(YF + (size_t)p * 64);
    const float* wb = cw + OF_WO6 + o0 * 64;

    float acc[16];
#pragma unroll
    for (int j = 0; j < 16; ++j) acc[j] = cw[OF_BO6 + o0 + j];

#pragma unroll
    for (int c = 0; c < 8; ++c) {
        uint4 u = yrow[c];
        float a0 = __uint_as_float(u.x << 16);
        float a1 = __uint_as_float(u.x & 0xFFFF0000u);
        float a2 = __uint_as_float(u.y << 16);
        float a3 = __uint_as_float(u.y & 0xFFFF0000u);
        float a4 = __uint_as_float(u.z << 16);
        float a5 = __uint_as_float(u.z & 0xFFFF0000u);
        float a6 = __uint_as_float(u.w << 16);
        float a7 = __uint_as_float(u.w & 0xFFFF0000u);
#pragma unroll
        for (int j = 0; j < 16; ++j) {
            const float* wr = wb + j * 64 + c * 8;
            acc[j] += a0 * wr[0] + a1 * wr[1] + a2 * wr[2] + a3 * wr[3]
                    + a4 * wr[4] + a5 * wr[5] + a6 * wr[6] + a7 * wr[7];
        }
    }

    const float f_y = cw[OF_FL0 + NPIX + p];
    const float f_x = cw[OF_FL0 + p];
    const float yf = (float)(p >> 6), xf = (float)(p & 63);
#pragma unroll
    for (int j = 0; j < 16; ++j) {
        int o = o0 + j;
        float val = 10.f * tanhf(acc[j]);
        int s = o >> 1;
        int a_idx = s % 9;
        if ((o & 1) == 0) py[s * NPIX + p] = val + f_y + (float)(a_idx / 3 - 1) + yf;
        else              px[s * NPIX + p] = val + f_x + (float)(a_idx % 3 - 1) + xf;
    }
}

// ---------------- deformable gather + attention, 8-thread teams ----------------
__device__ __forceinline__ float dot12(const bf16* __restrict__ row, const float* qv) {
    const uint2* s = (const uint2*)row;
    float d = 0.f;
#pragma unroll
    for (int c = 0; c < 3; ++c) {
        uint2 u = s[c];
        d += qv[c * 4 + 0] * __uint_as_float(u.x << 16);
        d += qv[c * 4 + 1] * __uint_as_float(u.x & 0xFFFF0000u);
        d += qv[c * 4 + 2] * __uint_as_float(u.y << 16);
        d += qv[c * 4 + 3] * __uint_as_float(u.y & 0xFFFF0000u);
    }
    return d;
}
__device__ __forceinline__ void acc12(float* ov, const bf16* __restrict__ row, float f) {
    const uint2* s = (const uint2*)row;
#pragma unroll
    for (int c = 0; c < 3; ++c) {
        uint2 u = s[c];
        ov[c * 4 + 0] += f * __uint_as_float(u.x << 16);
        ov[c * 4 + 1] += f * __uint_as_float(u.x & 0xFFFF0000u);
        ov[c * 4 + 2] += f * __uint_as_float(u.y << 16);
        ov[c * 4 + 3] += f * __uint_as_float(u.y & 0xFFFF0000u);
    }
}

__global__ __launch_bounds__(256) void attn_kernel(
    const bf16* __restrict__ qp, const bf16* __restrict__ kp,
    const bf16* __restrict__ vp, const float* __restrict__ py,
    const float* __restrict__ px, unsigned short* __restrict__ att)
{
    const int t = blockIdx.x * 256 + threadIdx.x;
    const int ch = t & 1;
    const int clip = (t >> 1) & 1;
    const int sh = (t >> 2) & 1;
    const int pp = t >> 3;
    const int m = pp >> 12;
    const int p = pp & 4095;

    float qv[12];
    {
        const uint2* s = (const uint2*)(qp + (size_t)(m * 4096 + p) * 24 + ch * 12);
#pragma unroll
        for (int c = 0; c < 3; ++c) {
            uint2 u = s[c];
            qv[c * 4 + 0] = __uint_as_float(u.x << 16);
            qv[c * 4 + 1] = __uint_as_float(u.x & 0xFFFF0000u);
            qv[c * 4 + 2] = __uint_as_float(u.y << 16);
            qv[c * 4 + 3] = __uint_as_float(u.y & 0xFFFF0000u);
        }
    }

    const int gidx = clip * 12 + m;
    const bf16* kb = kp + (size_t)gidx * 4096 * 24 + ch * 12;
    const bf16* vb = vp + (size_t)gidx * 4096 * 24 + ch * 12;
    const int sbase = gidx * 9;
    const int a0 = sh ? 5 : 0;
    const int na = sh ? 4 : 5;

    float e[5], fyv[5], fxv[5];
    float mx = -1e30f;
#pragma unroll
    for (int i = 0; i < 5; ++i) {
        e[i] = -1e30f; fyv[i] = 0.f; fxv[i] = 0.f;
        if (i < na) {
            const int a = a0 + i;
            const float fy = py[(sbase + a) * NPIX + p];
            const float fx = px[(sbase + a) * NPIX + p];
            fyv[i] = fy; fxv[i] = fx;
            const float y0 = floorf(fy), x0 = floorf(fx);
            const float wy = fy - y0, wx = fx - x0;
            const int iy = (int)y0, ix = (int)x0;
            const float w00 = (1.f - wy) * (1.f - wx), w01 = (1.f - wy) * wx;
            const float w10 = wy * (1.f - wx), w11 = wy * wx;
            float part = 0.f;
            if ((unsigned)iy < 64u) {
                const bf16* rr = kb + (size_t)(iy * 64) * 24;
                if ((unsigned)ix < 64u)       part += w00 * dot12(rr + ix * 24, qv);
                if ((unsigned)(ix + 1) < 64u) part += w01 * dot12(rr + (ix + 1) * 24, qv);
            }
            if ((unsigned)(iy + 1) < 64u) {
                const bf16* rr = kb + (size_t)((iy + 1) * 64) * 24;
                if ((unsigned)ix < 64u)       part += w10 * dot12(rr + ix * 24, qv);
                if ((unsigned)(ix + 1) < 64u) part += w11 * dot12(rr + (ix + 1) * 24, qv);
            }
            float full = part + __shfl_xor(part, 1, 64);
            e[i] = full * 0.20412414523193154f;
            mx = fmaxf(mx, e[i]);
        }
    }
    mx = fmaxf(mx, __shfl_xor(mx, 4, 64));
    mx = fmaxf(mx, __shfl_xor(mx, 2, 64));
    float sum = 0.f;
#pragma unroll
    for (int i = 0; i < 5; ++i) {
        if (i < na) { e[i] = __expf(e[i] - mx); sum += e[i]; }
    }
    sum += __shfl_xor(sum, 4, 64);
    sum += __shfl_xor(sum, 2, 64);
    const float inv = 1.f / sum;

    float ov[12];
#pragma unroll
    for (int j = 0; j < 12; ++j) ov[j] = 0.f;

#pragma unroll
    for (int i = 0; i < 5; ++i) {
        if (i < na) {
            const float wa = e[i] * inv;
            const float fy = fyv[i], fx = fxv[i];
            const float y0 = floorf(fy), x0 = floorf(fx);
            const float wy = fy - y0, wx = fx - x0;
            const int iy = (int)y0, ix = (int)x0;
            if ((unsigned)iy < 64u) {
                const bf16* rr = vb + (size_t)(iy * 64) * 24;
                if ((unsigned)ix < 64u)       acc12(ov, rr + ix * 24, wa * (1.f - wy) * (1.f - wx));
                if ((unsigned)(ix + 1) < 64u) acc12(ov, rr + (ix + 1) * 24, wa * (1.f - wy) * wx);
            }
            if ((unsigned)(iy + 1) < 64u) {
                const bf16* rr = vb + (size_t)((iy + 1) * 64) * 24;
                if ((unsigned)ix < 64u)       acc12(ov, rr + ix * 24, wa * wy * (1.f - wx));
                if ((unsigned)(ix + 1) < 64u) acc12(ov, rr + (ix + 1) * 24, wa * wy * wx);
            }
        }
    }
#pragma unroll
    for (int j = 0; j < 12; ++j) {
        ov[j] += __shfl_xor(ov[j], 4, 64);
        ov[j] += __shfl_xor(ov[j], 2, 64);
    }
    if (clip == 0 && sh == 0) {
        unsigned short* ab = att + (size_t)p * 288 + m * 24 + ch * 12;
#pragma unroll
        for (int c = 0; c < 3; ++c) {
            uint2 u;
            u.x = (unsigned)f2bu(ov[c * 4 + 0]) | ((unsigned)f2bu(ov[c * 4 + 1]) << 16);
            u.y = (unsigned)f2bu(ov[c * 4 + 2]) | ((unsigned)f2bu(ov[c * 4 + 3]) << 16);
            ((uint2*)ab)[c] = u;
        }
    }
}

// ---------------- diagnostic ----------------
__global__ void diag_kernel(float* __restrict__ out, int n, float v)
{
    int i = blockIdx.x * 256 + threadIdx.x;
    if (i < n) out[i] = (i == 0 ? v : 0.f);
}

extern "C" void kernel_launch(void* const* d_in, const int* in_sizes, int n_in,
                              void* d_out, int out_size, void* d_ws, size_t ws_size,
                              hipStream_t stream)
{
    const size_t REQUIRED = 23592960;
    if (ws_size < REQUIRED) {
        float code = 1000.0f + (float)(ws_size >> 20);
        diag_kernel<<<dim3((out_size + 255) / 256), 256, 0, stream>>>((float*)d_out, out_size, code);
        return;
    }

    char* W = (char*)d_ws;
    short* wsS = (short*)W;
    float* wsF = (float*)W;
    float* cw = (float*)(W + 64);

    const int OF_WO1 = 0,      OF_BO1 = 27904,  OF_WO2 = 27968,  OF_BO2 = 64832;
    const int OF_WO3 = 64896,  OF_BO3 = 101760, OF_WO4 = 101824, OF_BO4 = 138688;
    const int OF_WO5 = 138752, OF_BO5 = 175616, OF_WO6 = 175680, OF_BO6 = 203328;
    const int OF_WQ  = 203760, OF_BQ  = 245232, OF_WK  = 245520, OF_BK  = 286992;
    const int OF_WV  = 287280, OF_BV  = 328752, OF_WP  = 329040, OF_BP  = 370512;
    const int OF_WM1 = 370656, OF_BM1 = 412128, OF_WM2 = 412416, OF_BM2 = 453888;
    const int OF_FL0 = 454032, OF_FL1 = 462224;
    (void)OF_BO6; (void)OF_FL1;

    short* conv1w = wsS + 940864;
    short* conv3w0 = wsS + 969536;
    short* wqb = wsS + 1116992, *wkb = wsS + 1163072, *wvb = wsS + 1209152;
    short* wpS = wsS + 11658240, *wm1S = wsS + 11704320, *wm2S = wsS + 11750400;
    float* bpS = wsF + 5828544, *bm1S = wsF + 5828688, *bm2S = wsF + 5828976;
    bf16* QP = (bf16*)(W + 2786944);
    bf16* KP = (bf16*)(W + 5146240);
    bf16* VP = (bf16*)(W + 9864832);
    short* XS = (short*)(W + 14583424);
    short* X1 = XS;
    short* B3 = XS;
    short* Y0 = (short*)(W + 19302016);
    short* Y1 = (short*)(W + 19826304);
    short* YF = (short*)(W + 21661312);
    float* PY = (float*)(W + 14583424);
    float* PX = (float*)(W + 18122368);
    unsigned short* ATT = (unsigned short*)(W + 64);
    short* OPM = (short*)(W + 14583424);
    float* O32 = (float*)(W + 15894144);
    short* M1 = (short*)(W + 18253440);

    const unsigned short* qraw = (const unsigned short*)d_in[0];

    CArgs ca;
    const int srcidx[26] = {7,8,9,10,11,12,13,14,15,16,17,18,19,20,21,22,23,24,25,26,27,28,29,30,5,6};
    const int dsto[26]   = {OF_WO1,OF_BO1,OF_WO2,OF_BO2,OF_WO3,OF_BO3,OF_WO4,OF_BO4,OF_WO5,OF_BO5,
                            OF_WO6,203328,OF_WQ,OF_BQ,OF_WK,OF_BK,OF_WV,OF_BV,OF_WP,OF_BP,
                            OF_WM1,OF_BM1,OF_WM2,OF_BM2,OF_FL0,462224};
    for (int i = 0; i < 26; ++i) {
        ca.src[i] = d_in[srcidx[i]];
        ca.dstoff[i] = dsto[i];
        ca.n[i] = in_sizes[srcidx[i]];
    }
    convert_kernel<<<dim3(8, 26), 256, 0, stream>>>(ca, qraw, cw);

    PPArgs pp;
    pp.j[0]  = { 940864,  64, 448, 436, 64,  OF_WO1, 436, 0 };
    pp.j[1]  = { 969536,  64, 576, 576, 64,  OF_WO2, 576, 0 };
    pp.j[2]  = { 1006400, 64, 576, 576, 64,  OF_WO3, 576, 0 };
    pp.j[3]  = { 1043264, 64, 576, 576, 64,  OF_WO4, 576, 0 };
    pp.j[4]  = { 1080128, 64, 576, 576, 64,  OF_WO5, 576, 0 };
    pp.j[5]  = { 1116992, 288, 160, 144, 288, OF_WQ, 288, 1 };
    pp.j[6]  = { 1163072, 288, 160, 144, 288, OF_WK, 288, 1 };
    pp.j[7]  = { 1209152, 288, 160, 144, 288, OF_WV, 288, 1 };
    pp.j[8]  = { 11658240, 160, 288, 288, 144, OF_WP, 144, 1 };
    pp.j[9]  = { 11704320, 288, 160, 144, 288, OF_WM1, 288, 1 };
    pp.j[10] = { 11750400, 160, 288, 288, 144, OF_WM2, 144, 1 };
    prepack_kernel<<<dim3(64, 12), 256, 0, stream>>>(pp, cw, wsS, wsF);

    stage_pm_kernel<<<dim3(16, 2, 5), 256, 0, stream>>>(d_in[0], d_in[1], d_in[2], qraw, XS);

    GemmDesc5 gproj;
    const short* Xz[5] = { XS, XS + 655360, XS + 1310720, XS + 1966080, XS + 2621440 };
    const short* Az[5] = { wqb, wkb, wkb, wvb, wvb };
    const float* Bz[5] = { cw + OF_BQ, cw + OF_BK, cw + OF_BK, cw + OF_BV, cw + OF_BV };
    bf16* Dz[5] = { QP, KP, KP, VP, VP };
    const int Gz[5] = { 0, 0, 12, 0, 12 };
    for (int z = 0; z < 5; ++z)
        gproj.d[z] = { Az[z], Xz[z], Bz[z], Dz[z], nullptr, qraw, 288, 160, 288, 1, Gz[z] };
    gemm_kernel<2, 2><<<dim3(288, 1, 5), 256, 0, stream>>>(gproj);

    stage_x1_kernel<<<dim3(16, 4), 256, 0, stream>>>(d_in[0], d_in[3], d_in[4], cw, qraw, X1);

    GemmDesc5 g1;
    g1.d[0] = { conv1w, X1, cw + OF_BO1, Y0, nullptr, qraw, 64, 448, 64, 0, 0 };
    gemm_kernel<1, 1><<<dim3(256, 1, 1), 256, 0, stream>>>(g1);

    const float* cb[4] = { cw + OF_BO2, cw + OF_BO3, cw + OF_BO4, cw + OF_BO5 };
    short* cin[4] = { Y0, Y1, Y0, Y1 };
    short* cout[4] = { Y1, Y0, Y1, YF };
    for (int i = 0; i < 4; ++i) {
        im2col_kernel<<<dim3(128), 256, 0, stream>>>(cin[i], B3);
        GemmDesc5 g3;
        g3.d[0] = { conv3w0 + i * 36864, B3, cb[i], cout[i], nullptr, qraw, 64, 576, 64, 0, 0 };
        gemm_kernel<1, 1><<<dim3(256, 1, 1), 256, 0, stream>>>(g3);
    }

    conv6_kernel<<<dim3(16, 27), 256, 0, stream>>>(YF, cw, PY, PX);

    attn_kernel<<<dim3(1536), 256, 0, stream>>>(QP, KP, VP, PY, PX, ATT);

    GemmDesc5 gwp;
    gwp.d[0] = { wpS, (const short*)ATT, bpS, OPM, O32, qraw, 160, 288, 144, 3, 0 };
    gemm_kernel<2, 2><<<dim3(160, 1, 1), 256, 0, stream>>>(gwp);

    GemmDesc5 gm1;
    gm1.d[0] = { wm1S, OPM, bm1S, M1, nullptr, qraw, 288, 160, 288, 4, 0 };
    gemm_kernel<2, 2><<<dim3(288, 1, 1), 256, 0, stream>>>(gm1);

    GemmDesc5 gm2;
    gm2.d[0] = { wm2S, M1, bm2S, d_out, O32, qraw, 160, 288, 144, 5, 0 };
    gemm_kernel<2, 2><<<dim3(160, 1, 1), 256, 0, stream>>>(gm2);
}

// Round 10
// 304.446 us; speedup vs baseline: 1.4936x; 1.1151x over previous
//
#include <hip/hip_runtime.h>
#include <hip/hip_bf16.h>
#include <math.h>

typedef __hip_bfloat16 bf16;
typedef __attribute__((ext_vector_type(8))) short bf16x8v;
typedef __attribute__((ext_vector_type(4))) float f32x4v;

#define NPIX 4096

__device__ __forceinline__ float b2f(bf16 v) { return __bfloat162float(v); }
__device__ __forceinline__ unsigned short f2bu(float f) {
    bf16 h = __float2bfloat16(f);
    return *(unsigned short*)&h;
}
__device__ __forceinline__ int detect_bf16(const unsigned short* __restrict__ qraw) {
    int lane = threadIdx.x & 63;
    unsigned short u = qraw[lane * 2];
    int e = (u >> 7) & 0xFF;
    unsigned long long ball = __ballot(e >= 100 && e <= 135);
    return __popcll(ball) > 32;
}

// cw element offsets
#define OF_WO1 0
#define OF_BO1 27904
#define OF_WO2 27968
#define OF_BO2 64832
#define OF_WO3 64896
#define OF_BO3 101760
#define OF_WO4 101824
#define OF_BO4 138688
#define OF_WO5 138752
#define OF_BO5 175616
#define OF_WO6 175680
#define OF_BO6 203328
#define OF_WQ  203760
#define OF_BQ  245232
#define OF_WK  245520
#define OF_BK  286992
#define OF_WV  287280
#define OF_BV  328752
#define OF_WP  329040
#define OF_BP  370512
#define OF_WM1 370656
#define OF_BM1 412128
#define OF_WM2 412416
#define OF_BM2 453888
#define OF_FL0 454032
#define OF_FL1 462224

// ---------------- misc: convert(26) + stage_pm(10) + stage_x1(4) ----------------
struct CArgs { const void* src[26]; int dstoff[26]; int n[26]; };

__global__ void misc_kernel(CArgs a, const void* __restrict__ q, const void* __restrict__ k,
                            const void* __restrict__ v, const void* __restrict__ vp0,
                            const void* __restrict__ vp1, const void* __restrict__ fl0,
                            const void* __restrict__ fl1,
                            float* __restrict__ cw, short* __restrict__ XS, short* __restrict__ X1)
{
    const int isbf = detect_bf16((const unsigned short*)q);
    const int y = blockIdx.y;
    if (y < 26) {
        const int n = a.n[y];
        float* d = cw + a.dstoff[y];
        if (isbf) {
            const bf16* s = (const bf16*)a.src[y];
            for (int i = blockIdx.x * 256 + threadIdx.x; i < n; i += 256 * 16) d[i] = b2f(s[i]);
        } else {
            const float* s = (const float*)a.src[y];
            for (int i = blockIdx.x * 256 + threadIdx.x; i < n; i += 256 * 16) d[i] = s[i];
        }
    } else if (y < 36) {
        const int job = y - 26;
        const int z = job >> 1, half = job & 1;
        const int p = blockIdx.x * 256 + threadIdx.x;
        const void* srcs[5] = { q, k, k, v, v };
        const int clips[5] = { 0, 0, 1, 0, 1 };
        const size_t co = (size_t)clips[z] * 144 * NPIX;
        short* row = XS + (size_t)z * 655360 + (size_t)p * 160;
        for (int c0 = half * 72; c0 < half * 72 + 72; c0 += 8) {
            unsigned short h[8];
            if (isbf) {
                const bf16* s = (const bf16*)srcs[z] + co;
#pragma unroll
                for (int i = 0; i < 8; ++i) h[i] = f2bu(b2f(s[(size_t)(c0 + i) * NPIX + p]));
            } else {
                const float* s = (const float*)srcs[z] + co;
#pragma unroll
                for (int i = 0; i < 8; ++i) h[i] = f2bu(s[(size_t)(c0 + i) * NPIX + p]);
            }
            uint4 u;
            u.x = (unsigned)h[0] | ((unsigned)h[1] << 16);
            u.y = (unsigned)h[2] | ((unsigned)h[3] << 16);
            u.z = (unsigned)h[4] | ((unsigned)h[5] << 16);
            u.w = (unsigned)h[6] | ((unsigned)h[7] << 16);
            *(uint4*)(row + c0) = u;
        }
        if (half == 1) {
            uint4 zz; zz.x = zz.y = zz.z = zz.w = 0u;
            *(uint4*)(row + 144) = zz;
            *(uint4*)(row + 152) = zz;
        }
    } else {
        const int sec = y - 36;
        const int p = blockIdx.x * 256 + threadIdx.x;
        short* row = X1 + (size_t)p * 448;
        if (sec < 3) {
            const void* srcs[3] = { q, vp0, vp1 };
            const int cbase = sec * 144;
            for (int c0 = 0; c0 < 144; c0 += 8) {
                unsigned short h[8];
                if (isbf) {
                    const bf16* s = (const bf16*)srcs[sec];
#pragma unroll
                    for (int i = 0; i < 8; ++i) h[i] = f2bu(b2f(s[(size_t)(c0 + i) * NPIX + p]));
                } else {
                    const float* s = (const float*)srcs[sec];
#pragma unroll
                    for (int i = 0; i < 8; ++i) h[i] = f2bu(s[(size_t)(c0 + i) * NPIX + p]);
                }
                uint4 u;
                u.x = (unsigned)h[0] | ((unsigned)h[1] << 16);
                u.y = (unsigned)h[2] | ((unsigned)h[3] << 16);
                u.z = (unsigned)h[4] | ((unsigned)h[5] << 16);
                u.w = (unsigned)h[6] | ((unsigned)h[7] << 16);
                *(uint4*)(row + cbase + c0) = u;
            }
        } else {
            unsigned short h[4];
            if (isbf) {
                const bf16* f0 = (const bf16*)fl0;
                const bf16* f1 = (const bf16*)fl1;
                h[0] = f2bu(b2f(f0[p]));
                h[1] = f2bu(b2f(f0[NPIX + p]));
                h[2] = f2bu(b2f(f1[p]));
                h[3] = f2bu(b2f(f1[NPIX + p]));
            } else {
                const float* f0 = (const float*)fl0;
                const float* f1 = (const float*)fl1;
                h[0] = f2bu(f0[p]);
                h[1] = f2bu(f0[NPIX + p]);
                h[2] = f2bu(f1[p]);
                h[3] = f2bu(f1[NPIX + p]);
            }
            uint4 u;
            u.x = (unsigned)h[0] | ((unsigned)h[1] << 16);
            u.y = (unsigned)h[2] | ((unsigned)h[3] << 16);
            u.z = 0u; u.w = 0u;
            *(uint4*)(row + 432) = u;
            uint4 zz; zz.x = zz.y = zz.z = zz.w = 0u;
            *(uint4*)(row + 440) = zz;
        }
    }
}

// ---------------- prepack weights to bf16 [Mp][Kp] ----------------
// kind 0: row-major slice; kind 1: transpose; kind 2: conv3 K-reorder (k=tap*64+c -> src c*9+tap)
struct PPJob { int dstS; int Mp, Kp, kr, mr, srcof, sstride, kind; };
struct PPArgs { PPJob j[11]; };

__global__ void prepack_kernel(PPArgs pa, const float* __restrict__ cw, short* __restrict__ wsS)
{
    PPJob J = pa.j[blockIdx.y];
    const int tot = J.Mp * J.Kp;
    for (int e = blockIdx.x * 256 + threadIdx.x; e < tot; e += 256 * gridDim.x) {
        int m = e / J.Kp, kk = e - m * J.Kp;
        float v = 0.f;
        if (J.kind == 0) { if (kk < J.kr) v = cw[J.srcof + m * J.sstride + kk]; }
        else if (J.kind == 1) { if (kk < J.kr && m < J.mr) v = cw[J.srcof + kk * J.sstride + m]; }
        else { int c = kk & 63, tap = kk >> 6; if (kk < J.kr) v = cw[J.srcof + m * J.sstride + c * 9 + tap]; }
        wsS[J.dstS + e] = (short)f2bu(v);
    }
}

// ---------------- MFMA GEMM ----------------
struct GemmDesc {
    const short* A; const short* B; const float* bias;
    void* dst; void* dst2; const unsigned short* qraw;
    int Mp, Kp, Mreal, mode, gofs, nwaves;
};
struct GemmDesc6 { GemmDesc d[6]; };

// modes: 0 lrelu -> bf16 [p][Mp]; 1 proj -> [g][p][24]; 3 wp -> bf16 [p][160] + fp32 [p][144];
//        4 gelu -> bf16 [p][Mp]; 5 wm2 -> + residual -> d_out [m][4096]
// BM: 0 = B pixel-major [4096][Kp]; 1 = conv3 implicit im2col from Y [4096][64]
template <int TM, int TN, int BM>
__global__ __launch_bounds__(256) void gemm_kernel(GemmDesc6 gd)
{
    const GemmDesc d = gd.d[blockIdx.z];
    const int wid = blockIdx.x * 4 + (threadIdx.x >> 6);
    if (wid >= d.nwaves) return;
    const int lane = threadIdx.x & 63;
    const int tiles_m = d.Mp / (16 * TM);
    const int m0 = (wid % tiles_m) * (16 * TM);
    const int p0 = (wid / tiles_m) * (16 * TN);
    const int ar = lane & 15;
    const int kq = (lane >> 4) * 8;

    f32x4v acc[TM][TN];
#pragma unroll
    for (int i = 0; i < TM; ++i)
#pragma unroll
        for (int j = 0; j < TN; ++j) acc[i][j] = (f32x4v){0.f, 0.f, 0.f, 0.f};

    for (int k0 = 0; k0 < d.Kp; k0 += 32) {
        bf16x8v a[TM], b[TN];
#pragma unroll
        for (int i = 0; i < TM; ++i)
            a[i] = *(const bf16x8v*)(d.A + (size_t)(m0 + i * 16 + ar) * d.Kp + k0 + kq);
        if (BM == 0) {
#pragma unroll
            for (int j = 0; j < TN; ++j)
                b[j] = *(const bf16x8v*)(d.B + (size_t)(p0 + j * 16 + ar) * d.Kp + k0 + kq);
        } else {
            const int kk = k0 + kq;
            const int tap = kk >> 6, cc = kk & 63;
            const int dy = tap / 3 - 1, dx = tap % 3 - 1;
#pragma unroll
            for (int j = 0; j < TN; ++j) {
                const int pix = p0 + j * 16 + ar;
                const int yy = (pix >> 6) + dy, xx = (pix & 63) + dx;
                const bool ok = ((unsigned)yy < 64u) & ((unsigned)xx < 64u);
                const int np = min(max(yy, 0), 63) * 64 + min(max(xx, 0), 63);
                bf16x8v bv = *(const bf16x8v*)(d.B + (size_t)np * 64 + cc);
                if (!ok) bv = (bf16x8v)(short)0;
                b[j] = bv;
            }
        }
#pragma unroll
        for (int i = 0; i < TM; ++i)
#pragma unroll
            for (int j = 0; j < TN; ++j)
                acc[i][j] = __builtin_amdgcn_mfma_f32_16x16x32_bf16(a[i], b[j], acc[i][j], 0, 0, 0);
    }

    const int isbf = (d.mode == 5) ? detect_bf16(d.qraw) : 0;
#pragma unroll
    for (int i = 0; i < TM; ++i) {
#pragma unroll
        for (int j = 0; j < TN; ++j) {
            const int pcol = p0 + j * 16 + (lane & 15);
            const int mb = m0 + i * 16 + (lane >> 4) * 4;
            float vv[4];
#pragma unroll
            for (int r = 0; r < 4; ++r) {
                const int m = mb + r;
                vv[r] = acc[i][j][r];
                if (m < d.Mreal) vv[r] += d.bias[m];
            }
            if (d.mode == 0) {
#pragma unroll
                for (int r = 0; r < 4; ++r) vv[r] = (vv[r] >= 0.f) ? vv[r] : 0.1f * vv[r];
                uint2 u;
                u.x = (unsigned)f2bu(vv[0]) | ((unsigned)f2bu(vv[1]) << 16);
                u.y = (unsigned)f2bu(vv[2]) | ((unsigned)f2bu(vv[3]) << 16);
                *(uint2*)((unsigned short*)d.dst + (size_t)pcol * d.Mp + mb) = u;
            } else if (d.mode == 1) {
                const int g = mb / 24 + d.gofs;
                uint2 u;
                u.x = (unsigned)f2bu(vv[0]) | ((unsigned)f2bu(vv[1]) << 16);
                u.y = (unsigned)f2bu(vv[2]) | ((unsigned)f2bu(vv[3]) << 16);
                *(uint2*)((unsigned short*)d.dst + ((size_t)g * NPIX + pcol) * 24 + (mb % 24)) = u;
            } else if (d.mode == 3) {
                uint2 u;
                u.x = (unsigned)f2bu(vv[0]) | ((unsigned)f2bu(vv[1]) << 16);
                u.y = (unsigned)f2bu(vv[2]) | ((unsigned)f2bu(vv[3]) << 16);
                *(uint2*)((unsigned short*)d.dst + (size_t)pcol * 160 + mb) = u;
                if (mb < 144)
                    *(float4*)((float*)d.dst2 + (size_t)pcol * 144 + mb) =
                        make_float4(vv[0], vv[1], vv[2], vv[3]);
            } else if (d.mode == 4) {
#pragma unroll
                for (int r = 0; r < 4; ++r)
                    vv[r] = 0.5f * vv[r] * (1.f + erff(vv[r] * 0.70710678118654752f));
                uint2 u;
                u.x = (unsigned)f2bu(vv[0]) | ((unsigned)f2bu(vv[1]) << 16);
                u.y = (unsigned)f2bu(vv[2]) | ((unsigned)f2bu(vv[3]) << 16);
                *(uint2*)((unsigned short*)d.dst + (size_t)pcol * d.Mp + mb) = u;
            } else { // 5
#pragma unroll
                for (int r = 0; r < 4; ++r) {
                    const int m = mb + r;
                    if (m < 144) {
                        float v = vv[r] + ((float*)d.dst2)[(size_t)pcol * 144 + m];
                        if (isbf) ((unsigned short*)d.dst)[(size_t)m * NPIX + pcol] = f2bu(v);
                        else      ((float*)d.dst)[(size_t)m * NPIX + pcol] = v;
                    }
                }
            }
        }
    }
}

// ---------------- conv6: static-unrolled ----------------
__global__ __launch_bounds__(256) void conv6_kernel(const short* __restrict__ YF,
                                                    const float* __restrict__ cw,
                                                    float* __restrict__ py, float* __restrict__ px)
{
    const int p = blockIdx.x * 256 + threadIdx.x;
    const int o0 = blockIdx.y * 16;
    const uint4* yrow = (const uint4*)(YF + (size_t)p * 64);
    const float* wb = cw + OF_WO6 + o0 * 64;

    float acc[16];
#pragma unroll
    for (int j = 0; j < 16; ++j) acc[j] = cw[OF_BO6 + o0 + j];

#pragma unroll
    for (int c = 0; c < 8; ++c) {
        uint4 u = yrow[c];
        float a0 = __uint_as_float(u.x << 16);
        float a1 = __uint_as_float(u.x & 0xFFFF0000u);
        float a2 = __uint_as_float(u.y << 16);
        float a3 = __uint_as_float(u.y & 0xFFFF0000u);
        float a4 = __uint_as_float(u.z << 16);
        float a5 = __uint_as_float(u.z & 0xFFFF0000u);
        float a6 = __uint_as_float(u.w << 16);
        float a7 = __uint_as_float(u.w & 0xFFFF0000u);
#pragma unroll
        for (int j = 0; j < 16; ++j) {
            const float* wr = wb + j * 64 + c * 8;
            acc[j] += a0 * wr[0] + a1 * wr[1] + a2 * wr[2] + a3 * wr[3]
                    + a4 * wr[4] + a5 * wr[5] + a6 * wr[6] + a7 * wr[7];
        }
    }

    const float f_y = cw[OF_FL0 + NPIX + p];
    const float f_x = cw[OF_FL0 + p];
    const float yf = (float)(p >> 6), xf = (float)(p & 63);
#pragma unroll
    for (int j = 0; j < 16; ++j) {
        int o = o0 + j;
        float val = 10.f * tanhf(acc[j]);
        int s = o >> 1;
        int a_idx = s % 9;
        if ((o & 1) == 0) py[s * NPIX + p] = val + f_y + (float)(a_idx / 3 - 1) + yf;
        else              px[s * NPIX + p] = val + f_x + (float)(a_idx % 3 - 1) + xf;
    }
}

// ---------------- deformable gather + attention, 8-thread teams ----------------
__device__ __forceinline__ float dot12(const bf16* __restrict__ row, const float* qv) {
    const uint2* s = (const uint2*)row;
    float d = 0.f;
#pragma unroll
    for (int c = 0; c < 3; ++c) {
        uint2 u = s[c];
        d += qv[c * 4 + 0] * __uint_as_float(u.x << 16);
        d += qv[c * 4 + 1] * __uint_as_float(u.x & 0xFFFF0000u);
        d += qv[c * 4 + 2] * __uint_as_float(u.y << 16);
        d += qv[c * 4 + 3] * __uint_as_float(u.y & 0xFFFF0000u);
    }
    return d;
}
__device__ __forceinline__ void acc12(float* ov, const bf16* __restrict__ row, float f) {
    const uint2* s = (const uint2*)row;
#pragma unroll
    for (int c = 0; c < 3; ++c) {
        uint2 u = s[c];
        ov[c * 4 + 0] += f * __uint_as_float(u.x << 16);
        ov[c * 4 + 1] += f * __uint_as_float(u.x & 0xFFFF0000u);
        ov[c * 4 + 2] += f * __uint_as_float(u.y << 16);
        ov[c * 4 + 3] += f * __uint_as_float(u.y & 0xFFFF0000u);
    }
}

__global__ __launch_bounds__(256) void attn_kernel(
    const bf16* __restrict__ qp, const bf16* __restrict__ kp,
    const bf16* __restrict__ vp, const float* __restrict__ py,
    const float* __restrict__ px, unsigned short* __restrict__ att)
{
    const int t = blockIdx.x * 256 + threadIdx.x;
    const int ch = t & 1;
    const int clip = (t >> 1) & 1;
    const int sh = (t >> 2) & 1;
    const int pp = t >> 3;
    const int m = pp >> 12;
    const int p = pp & 4095;

    float qv[12];
    {
        const uint2* s = (const uint2*)(qp + (size_t)(m * 4096 + p) * 24 + ch * 12);
#pragma unroll
        for (int c = 0; c < 3; ++c) {
            uint2 u = s[c];
            qv[c * 4 + 0] = __uint_as_float(u.x << 16);
            qv[c * 4 + 1] = __uint_as_float(u.x & 0xFFFF0000u);
            qv[c * 4 + 2] = __uint_as_float(u.y << 16);
            qv[c * 4 + 3] = __uint_as_float(u.y & 0xFFFF0000u);
        }
    }

    const int gidx = clip * 12 + m;
    const bf16* kb = kp + (size_t)gidx * 4096 * 24 + ch * 12;
    const bf16* vb = vp + (size_t)gidx * 4096 * 24 + ch * 12;
    const int sbase = gidx * 9;
    const int a0 = sh ? 5 : 0;
    const int na = sh ? 4 : 5;

    float e[5], fyv[5], fxv[5];
    float mx = -1e30f;
#pragma unroll
    for (int i = 0; i < 5; ++i) {
        e[i] = -1e30f; fyv[i] = 0.f; fxv[i] = 0.f;
        if (i < na) {
            const int a = a0 + i;
            const float fy = py[(sbase + a) * NPIX + p];
            const float fx = px[(sbase + a) * NPIX + p];
            fyv[i] = fy; fxv[i] = fx;
            const float y0 = floorf(fy), x0 = floorf(fx);
            const float wy = fy - y0, wx = fx - x0;
            const int iy = (int)y0, ix = (int)x0;
            const float w00 = (1.f - wy) * (1.f - wx), w01 = (1.f - wy) * wx;
            const float w10 = wy * (1.f - wx), w11 = wy * wx;
            float part = 0.f;
            if ((unsigned)iy < 64u) {
                const bf16* rr = kb + (size_t)(iy * 64) * 24;
                if ((unsigned)ix < 64u)       part += w00 * dot12(rr + ix * 24, qv);
                if ((unsigned)(ix + 1) < 64u) part += w01 * dot12(rr + (ix + 1) * 24, qv);
            }
            if ((unsigned)(iy + 1) < 64u) {
                const bf16* rr = kb + (size_t)((iy + 1) * 64) * 24;
                if ((unsigned)ix < 64u)       part += w10 * dot12(rr + ix * 24, qv);
                if ((unsigned)(ix + 1) < 64u) part += w11 * dot12(rr + (ix + 1) * 24, qv);
            }
            float full = part + __shfl_xor(part, 1, 64);
            e[i] = full * 0.20412414523193154f;
            mx = fmaxf(mx, e[i]);
        }
    }
    mx = fmaxf(mx, __shfl_xor(mx, 4, 64));
    mx = fmaxf(mx, __shfl_xor(mx, 2, 64));
    float sum = 0.f;
#pragma unroll
    for (int i = 0; i < 5; ++i) {
        if (i < na) { e[i] = __expf(e[i] - mx); sum += e[i]; }
    }
    sum += __shfl_xor(sum, 4, 64);
    sum += __shfl_xor(sum, 2, 64);
    const float inv = 1.f / sum;

    float ov[12];
#pragma unroll
    for (int j = 0; j < 12; ++j) ov[j] = 0.f;

#pragma unroll
    for (int i = 0; i < 5; ++i) {
        if (i < na) {
            const float wa = e[i] * inv;
            const float fy = fyv[i], fx = fxv[i];
            const float y0 = floorf(fy), x0 = floorf(fx);
            const float wy = fy - y0, wx = fx - x0;
            const int iy = (int)y0, ix = (int)x0;
            if ((unsigned)iy < 64u) {
                const bf16* rr = vb + (size_t)(iy * 64) * 24;
                if ((unsigned)ix < 64u)       acc12(ov, rr + ix * 24, wa * (1.f - wy) * (1.f - wx));
                if ((unsigned)(ix + 1) < 64u) acc12(ov, rr + (ix + 1) * 24, wa * (1.f - wy) * wx);
            }
            if ((unsigned)(iy + 1) < 64u) {
                const bf16* rr = vb + (size_t)((iy + 1) * 64) * 24;
                if ((unsigned)ix < 64u)       acc12(ov, rr + ix * 24, wa * wy * (1.f - wx));
                if ((unsigned)(ix + 1) < 64u) acc12(ov, rr + (ix + 1) * 24, wa * wy * wx);
            }
        }
    }
#pragma unroll
    for (int j = 0; j < 12; ++j) {
        ov[j] += __shfl_xor(ov[j], 4, 64);
        ov[j] += __shfl_xor(ov[j], 2, 64);
    }
    if (clip == 0 && sh == 0) {
        unsigned short* ab = att + (size_t)p * 288 + m * 24 + ch * 12;
#pragma unroll
        for (int c = 0; c < 3; ++c) {
            uint2 u;
            u.x = (unsigned)f2bu(ov[c * 4 + 0]) | ((unsigned)f2bu(ov[c * 4 + 1]) << 16);
            u.y = (unsigned)f2bu(ov[c * 4 + 2]) | ((unsigned)f2bu(ov[c * 4 + 3]) << 16);
            ((uint2*)ab)[c] = u;
        }
    }
}

// ---------------- diagnostic ----------------
__global__ void diag_kernel(float* __restrict__ out, int n, float v)
{
    int i = blockIdx.x * 256 + threadIdx.x;
    if (i < n) out[i] = (i == 0 ? v : 0.f);
}

extern "C" void kernel_launch(void* const* d_in, const int* in_sizes, int n_in,
                              void* d_out, int out_size, void* d_ws, size_t ws_size,
                              hipStream_t stream)
{
    const size_t REQUIRED = 75000000;   // observed ws_size = 256 MiB (poison-fill WRITE_SIZE)
    if (ws_size < REQUIRED) {
        float code = 1000.0f + (float)(ws_size >> 20);
        diag_kernel<<<dim3((out_size + 255) / 256), 256, 0, stream>>>((float*)d_out, out_size, code);
        return;
    }

    char* W = (char*)d_ws;
    short* wsS = (short*)W;
    float* cw = (float*)(W + 64);

    // packed weight bases (short indices)
    short* conv1w = wsS + 1000000;
    short* conv3w[4] = { wsS + 1028672, wsS + 1065536, wsS + 1102400, wsS + 1139264 };
    short* wqb = wsS + 1176128, *wkb = wsS + 1222208, *wvb = wsS + 1268288;
    short* wpS = wsS + 1314368, *wm1S = wsS + 1360448, *wm2S = wsS + 1406528;

    short* XS = (short*)(W + 16777216);
    short* X1 = (short*)(W + 25165824);
    bf16*  QP = (bf16*)(W + 33554432);
    bf16*  KP = (bf16*)(W + 36700160);
    bf16*  VP = (bf16*)(W + 41943040);
    short* Y0 = (short*)(W + 50331648);
    short* Y1 = (short*)(W + 50855936);
    short* YF = (short*)(W + 51380224);
    float* PY = (float*)(W + 54525952);
    float* PX = (float*)(W + 58064896);
    unsigned short* ATT = (unsigned short*)(W + 62914560);
    short* OPM = (short*)(W + 67108864);
    float* O32 = (float*)(W + 68419584);
    short* M1  = (short*)(W + 71303168);

    const unsigned short* qraw = (const unsigned short*)d_in[0];

    // 1. convert + stage_pm + stage_x1
    CArgs ca;
    const int srcidx[26] = {7,8,9,10,11,12,13,14,15,16,17,18,19,20,21,22,23,24,25,26,27,28,29,30,5,6};
    const int dsto[26]   = {OF_WO1,OF_BO1,OF_WO2,OF_BO2,OF_WO3,OF_BO3,OF_WO4,OF_BO4,OF_WO5,OF_BO5,
                            OF_WO6,OF_BO6,OF_WQ,OF_BQ,OF_WK,OF_BK,OF_WV,OF_BV,OF_WP,OF_BP,
                            OF_WM1,OF_BM1,OF_WM2,OF_BM2,OF_FL0,OF_FL1};
    for (int i = 0; i < 26; ++i) {
        ca.src[i] = d_in[srcidx[i]];
        ca.dstoff[i] = dsto[i];
        ca.n[i] = in_sizes[srcidx[i]];
    }
    misc_kernel<<<dim3(16, 40), 256, 0, stream>>>(ca, d_in[0], d_in[1], d_in[2], d_in[3], d_in[4],
                                                  d_in[5], d_in[6], cw, XS, X1);

    // 2. prepack weights
    PPArgs pp;
    pp.j[0]  = { 1000000, 64, 448, 436, 64,  OF_WO1, 436, 0 };
    pp.j[1]  = { 1028672, 64, 576, 576, 64,  OF_WO2, 576, 2 };
    pp.j[2]  = { 1065536, 64, 576, 576, 64,  OF_WO3, 576, 2 };
    pp.j[3]  = { 1102400, 64, 576, 576, 64,  OF_WO4, 576, 2 };
    pp.j[4]  = { 1139264, 64, 576, 576, 64,  OF_WO5, 576, 2 };
    pp.j[5]  = { 1176128, 288, 160, 144, 288, OF_WQ, 288, 1 };
    pp.j[6]  = { 1222208, 288, 160, 144, 288, OF_WK, 288, 1 };
    pp.j[7]  = { 1268288, 288, 160, 144, 288, OF_WV, 288, 1 };
    pp.j[8]  = { 1314368, 160, 288, 288, 144, OF_WP, 144, 1 };
    pp.j[9]  = { 1360448, 288, 160, 144, 288, OF_WM1, 288, 1 };
    pp.j[10] = { 1406528, 160, 288, 288, 144, OF_WM2, 144, 1 };
    prepack_kernel<<<dim3(64, 11), 256, 0, stream>>>(pp, cw, wsS);

    // 3. proj x5 + conv1 in one GEMM dispatch
    GemmDesc6 g3;
    const short* Xz[5] = { XS, XS + 655360, XS + 1310720, XS + 1966080, XS + 2621440 };
    const short* Az[5] = { wqb, wkb, wkb, wvb, wvb };
    const float* Bz[5] = { cw + OF_BQ, cw + OF_BK, cw + OF_BK, cw + OF_BV, cw + OF_BV };
    bf16* Dz[5] = { QP, KP, KP, VP, VP };
    const int Gz[5] = { 0, 0, 12, 0, 12 };
    for (int z = 0; z < 5; ++z)
        g3.d[z] = { Az[z], Xz[z], Bz[z], Dz[z], nullptr, qraw, 288, 160, 288, 1, Gz[z], 1152 };
    g3.d[5] = { conv1w, X1, cw + OF_BO1, Y0, nullptr, qraw, 64, 448, 64, 0, 0, 256 };
    gemm_kernel<2, 2, 0><<<dim3(288, 1, 6), 256, 0, stream>>>(g3);

    // 4-7. conv3 chain, implicit-im2col GEMMs
    const float* cb[4] = { cw + OF_BO2, cw + OF_BO3, cw + OF_BO4, cw + OF_BO5 };
    short* cin[4] = { Y0, Y1, Y0, Y1 };
    short* coutp[4] = { Y1, Y0, Y1, YF };
    for (int i = 0; i < 4; ++i) {
        GemmDesc6 gc;
        gc.d[0] = { conv3w[i], cin[i], cb[i], coutp[i], nullptr, qraw, 64, 576, 64, 0, 0, 256 };
        gemm_kernel<2, 2, 1><<<dim3(64, 1, 1), 256, 0, stream>>>(gc);
    }

    // 8. conv6 -> py/px
    conv6_kernel<<<dim3(16, 27), 256, 0, stream>>>(YF, cw, PY, PX);

    // 9. attention
    attn_kernel<<<dim3(1536), 256, 0, stream>>>(QP, KP, VP, PY, PX, ATT);

    // 10. wp GEMM
    GemmDesc6 gwp;
    gwp.d[0] = { wpS, (const short*)ATT, cw + OF_BP, OPM, O32, qraw, 160, 288, 144, 3, 0, 640 };
    gemm_kernel<2, 2, 0><<<dim3(160, 1, 1), 256, 0, stream>>>(gwp);

    // 11. wm1 GEMM + gelu
    GemmDesc6 gm1;
    gm1.d[0] = { wm1S, OPM, cw + OF_BM1, M1, nullptr, qraw, 288, 160, 288, 4, 0, 1152 };
    gemm_kernel<2, 2, 0><<<dim3(288, 1, 1), 256, 0, stream>>>(gm1);

    // 12. wm2 GEMM + residual -> d_out
    GemmDesc6 gm2;
    gm2.d[0] = { wm2S, M1, cw + OF_BM2, d_out, O32, qraw, 160, 288, 144, 5, 0, 640 };
    gemm_kernel<2, 2, 0><<<dim3(160, 1, 1), 256, 0, stream>>>(gm2);
}

// Round 11
// 279.813 us; speedup vs baseline: 1.6251x; 1.0880x over previous
//
#include <hip/hip_runtime.h>
#include <hip/hip_bf16.h>
#include <math.h>

typedef __hip_bfloat16 bf16;
typedef __attribute__((ext_vector_type(8))) short bf16x8v;
typedef __attribute__((ext_vector_type(4))) float f32x4v;

#define NPIX 4096

__device__ __forceinline__ float b2f(bf16 v) { return __bfloat162float(v); }
__device__ __forceinline__ unsigned short f2bu(float f) {
    bf16 h = __float2bfloat16(f);
    return *(unsigned short*)&h;
}
__device__ __forceinline__ int detect_bf16(const unsigned short* __restrict__ qraw) {
    int lane = threadIdx.x & 63;
    unsigned short u = qraw[lane * 2];
    int e = (u >> 7) & 0xFF;
    unsigned long long ball = __ballot(e >= 100 && e <= 135);
    return __popcll(ball) > 32;
}
__device__ __forceinline__ float rdval(const void* s, int idx, int isbf) {
    return isbf ? b2f(((const bf16*)s)[idx]) : ((const float*)s)[idx];
}

// cw element offsets
#define OF_WO6 175680
#define OF_BO6 203328
#define OF_BO1 27904
#define OF_BO2 64832
#define OF_BO3 101760
#define OF_BO4 138688
#define OF_BO5 175616
#define OF_BQ  245232
#define OF_BK  286992
#define OF_BV  328752
#define OF_BP  370512
#define OF_BM1 412128
#define OF_BM2 453888
#define OF_FL0 454032

// ---------------- fused: convert(26) + stage_pm(10) + stage_x1(4) + prepack(11) ----------------
struct CArgs { const void* src[26]; int dstoff[26]; int n[26]; };
struct PPJob { const void* src; int dstS; int Mp, Kp, kr, mr, sstride, kind; };
struct PPArgs { PPJob j[11]; };

__global__ void misc_kernel(CArgs a, PPArgs pa, const void* __restrict__ q,
                            const void* __restrict__ k, const void* __restrict__ v,
                            const void* __restrict__ vp0, const void* __restrict__ vp1,
                            const void* __restrict__ fl0, const void* __restrict__ fl1,
                            float* __restrict__ cw, short* __restrict__ XS,
                            short* __restrict__ X1, short* __restrict__ wsS)
{
    const int isbf = detect_bf16((const unsigned short*)q);
    const int y = blockIdx.y;
    if (y < 26) {
        const int n = a.n[y];
        float* d = cw + a.dstoff[y];
        if (isbf) {
            const bf16* s = (const bf16*)a.src[y];
            for (int i = blockIdx.x * 256 + threadIdx.x; i < n; i += 256 * 16) d[i] = b2f(s[i]);
        } else {
            const float* s = (const float*)a.src[y];
            for (int i = blockIdx.x * 256 + threadIdx.x; i < n; i += 256 * 16) d[i] = s[i];
        }
    } else if (y < 36) {
        const int job = y - 26;
        const int z = job >> 1, half = job & 1;
        const int p = blockIdx.x * 256 + threadIdx.x;
        const void* srcs[5] = { q, k, k, v, v };
        const int clips[5] = { 0, 0, 1, 0, 1 };
        const size_t co = (size_t)clips[z] * 144 * NPIX;
        short* row = XS + (size_t)z * 655360 + (size_t)p * 160;
        for (int c0 = half * 72; c0 < half * 72 + 72; c0 += 8) {
            unsigned short h[8];
            if (isbf) {
                const bf16* s = (const bf16*)srcs[z] + co;
#pragma unroll
                for (int i = 0; i < 8; ++i) h[i] = f2bu(b2f(s[(size_t)(c0 + i) * NPIX + p]));
            } else {
                const float* s = (const float*)srcs[z] + co;
#pragma unroll
                for (int i = 0; i < 8; ++i) h[i] = f2bu(s[(size_t)(c0 + i) * NPIX + p]);
            }
            uint4 u;
            u.x = (unsigned)h[0] | ((unsigned)h[1] << 16);
            u.y = (unsigned)h[2] | ((unsigned)h[3] << 16);
            u.z = (unsigned)h[4] | ((unsigned)h[5] << 16);
            u.w = (unsigned)h[6] | ((unsigned)h[7] << 16);
            *(uint4*)(row + c0) = u;
        }
        if (half == 1) {
            uint4 zz; zz.x = zz.y = zz.z = zz.w = 0u;
            *(uint4*)(row + 144) = zz;
            *(uint4*)(row + 152) = zz;
        }
    } else if (y < 40) {
        const int sec = y - 36;
        const int p = blockIdx.x * 256 + threadIdx.x;
        short* row = X1 + (size_t)p * 448;
        if (sec < 3) {
            const void* srcs[3] = { q, vp0, vp1 };
            const int cbase = sec * 144;
            for (int c0 = 0; c0 < 144; c0 += 8) {
                unsigned short h[8];
                if (isbf) {
                    const bf16* s = (const bf16*)srcs[sec];
#pragma unroll
                    for (int i = 0; i < 8; ++i) h[i] = f2bu(b2f(s[(size_t)(c0 + i) * NPIX + p]));
                } else {
                    const float* s = (const float*)srcs[sec];
#pragma unroll
                    for (int i = 0; i < 8; ++i) h[i] = f2bu(s[(size_t)(c0 + i) * NPIX + p]);
                }
                uint4 u;
                u.x = (unsigned)h[0] | ((unsigned)h[1] << 16);
                u.y = (unsigned)h[2] | ((unsigned)h[3] << 16);
                u.z = (unsigned)h[4] | ((unsigned)h[5] << 16);
                u.w = (unsigned)h[6] | ((unsigned)h[7] << 16);
                *(uint4*)(row + cbase + c0) = u;
            }
        } else {
            unsigned short h[4];
            if (isbf) {
                const bf16* f0 = (const bf16*)fl0;
                const bf16* f1 = (const bf16*)fl1;
                h[0] = f2bu(b2f(f0[p]));
                h[1] = f2bu(b2f(f0[NPIX + p]));
                h[2] = f2bu(b2f(f1[p]));
                h[3] = f2bu(b2f(f1[NPIX + p]));
            } else {
                const float* f0 = (const float*)fl0;
                const float* f1 = (const float*)fl1;
                h[0] = f2bu(f0[p]);
                h[1] = f2bu(f0[NPIX + p]);
                h[2] = f2bu(f1[p]);
                h[3] = f2bu(f1[NPIX + p]);
            }
            uint4 u;
            u.x = (unsigned)h[0] | ((unsigned)h[1] << 16);
            u.y = (unsigned)h[2] | ((unsigned)h[3] << 16);
            u.z = 0u; u.w = 0u;
            *(uint4*)(row + 432) = u;
            uint4 zz; zz.x = zz.y = zz.z = zz.w = 0u;
            *(uint4*)(row + 440) = zz;
        }
    } else {
        // prepack job (reads d_in directly, dual dtype)
        PPJob J = pa.j[y - 40];
        const int tot = J.Mp * J.Kp;
        for (int e = blockIdx.x * 256 + threadIdx.x; e < tot; e += 256 * 16) {
            int m = e / J.Kp, kk = e - m * J.Kp;
            float vv = 0.f;
            if (J.kind == 0) { if (kk < J.kr) vv = rdval(J.src, m * J.sstride + kk, isbf); }
            else if (J.kind == 1) { if (kk < J.kr && m < J.mr) vv = rdval(J.src, kk * J.sstride + m, isbf); }
            else { int c = kk & 63, tap = kk >> 6; if (kk < J.kr) vv = rdval(J.src, m * J.sstride + c * 9 + tap, isbf); }
            wsS[J.dstS + e] = (short)f2bu(vv);
        }
    }
}

// ---------------- MFMA GEMM (KP compile-time -> fully unrolled K-loop) ----------------
struct GemmDesc {
    const short* A; const short* B; const float* bias;
    void* dst; void* dst2; const unsigned short* qraw;
    int Mp, Mreal, mode, gofs, nwaves;
};
struct GemmDesc5 { GemmDesc d[5]; };

// modes: 0 lrelu -> bf16 [p][Mp]; 1 proj -> [g][p][24]; 3 wp -> bf16 [p][160] + fp32 [p][144];
//        4 gelu -> bf16 [p][Mp]; 5 wm2 -> + residual -> d_out [m][4096]
// BM: 0 = B pixel-major [4096][KP]; 1 = implicit im2col from Y [4096][64] (KP=576)
template <int TM, int TN, int BM, int KP>
__global__ __launch_bounds__(256) void gemm_kernel(GemmDesc5 gd)
{
    const GemmDesc d = gd.d[blockIdx.z];
    const int wid = blockIdx.x * 4 + (threadIdx.x >> 6);
    if (wid >= d.nwaves) return;
    const int lane = threadIdx.x & 63;
    const int tiles_m = d.Mp / (16 * TM);
    const int m0 = (wid % tiles_m) * (16 * TM);
    const int p0 = (wid / tiles_m) * (16 * TN);
    const int ar = lane & 15;
    const int kq = (lane >> 4) * 8;

    f32x4v acc[TM][TN];
#pragma unroll
    for (int i = 0; i < TM; ++i)
#pragma unroll
        for (int j = 0; j < TN; ++j) acc[i][j] = (f32x4v){0.f, 0.f, 0.f, 0.f};

#pragma unroll
    for (int k0 = 0; k0 < KP; k0 += 32) {
        bf16x8v a[TM], b[TN];
#pragma unroll
        for (int i = 0; i < TM; ++i)
            a[i] = *(const bf16x8v*)(d.A + (size_t)(m0 + i * 16 + ar) * KP + k0 + kq);
        if (BM == 0) {
#pragma unroll
            for (int j = 0; j < TN; ++j)
                b[j] = *(const bf16x8v*)(d.B + (size_t)(p0 + j * 16 + ar) * KP + k0 + kq);
        } else {
            const int tap = k0 >> 6;               // compile-time (kq<32, k0%32==0)
            const int cc = (k0 & 63) + kq;
            const int dy = tap / 3 - 1, dx = tap % 3 - 1;
#pragma unroll
            for (int j = 0; j < TN; ++j) {
                const int pix = p0 + j * 16 + ar;
                const int yy = (pix >> 6) + dy, xx = (pix & 63) + dx;
                const bool ok = ((unsigned)yy < 64u) & ((unsigned)xx < 64u);
                const int np = min(max(yy, 0), 63) * 64 + min(max(xx, 0), 63);
                bf16x8v bv = *(const bf16x8v*)(d.B + (size_t)np * 64 + cc);
                if (!ok) bv = (bf16x8v)(short)0;
                b[j] = bv;
            }
        }
#pragma unroll
        for (int i = 0; i < TM; ++i)
#pragma unroll
            for (int j = 0; j < TN; ++j)
                acc[i][j] = __builtin_amdgcn_mfma_f32_16x16x32_bf16(a[i], b[j], acc[i][j], 0, 0, 0);
    }

    const int isbf = (d.mode == 5) ? detect_bf16(d.qraw) : 0;
#pragma unroll
    for (int i = 0; i < TM; ++i) {
#pragma unroll
        for (int j = 0; j < TN; ++j) {
            const int pcol = p0 + j * 16 + (lane & 15);
            const int mb = m0 + i * 16 + (lane >> 4) * 4;
            float vv[4];
#pragma unroll
            for (int r = 0; r < 4; ++r) {
                const int m = mb + r;
                vv[r] = acc[i][j][r];
                if (m < d.Mreal) vv[r] += d.bias[m];
            }
            if (d.mode == 0) {
#pragma unroll
                for (int r = 0; r < 4; ++r) vv[r] = (vv[r] >= 0.f) ? vv[r] : 0.1f * vv[r];
                uint2 u;
                u.x = (unsigned)f2bu(vv[0]) | ((unsigned)f2bu(vv[1]) << 16);
                u.y = (unsigned)f2bu(vv[2]) | ((unsigned)f2bu(vv[3]) << 16);
                *(uint2*)((unsigned short*)d.dst + (size_t)pcol * d.Mp + mb) = u;
            } else if (d.mode == 1) {
                const int g = mb / 24 + d.gofs;
                uint2 u;
                u.x = (unsigned)f2bu(vv[0]) | ((unsigned)f2bu(vv[1]) << 16);
                u.y = (unsigned)f2bu(vv[2]) | ((unsigned)f2bu(vv[3]) << 16);
                *(uint2*)((unsigned short*)d.dst + ((size_t)g * NPIX + pcol) * 24 + (mb % 24)) = u;
            } else if (d.mode == 3) {
                uint2 u;
                u.x = (unsigned)f2bu(vv[0]) | ((unsigned)f2bu(vv[1]) << 16);
                u.y = (unsigned)f2bu(vv[2]) | ((unsigned)f2bu(vv[3]) << 16);
                *(uint2*)((unsigned short*)d.dst + (size_t)pcol * 160 + mb) = u;
                if (mb < 144)
                    *(float4*)((float*)d.dst2 + (size_t)pcol * 144 + mb) =
                        make_float4(vv[0], vv[1], vv[2], vv[3]);
            } else if (d.mode == 4) {
#pragma unroll
                for (int r = 0; r < 4; ++r)
                    vv[r] = 0.5f * vv[r] * (1.f + erff(vv[r] * 0.70710678118654752f));
                uint2 u;
                u.x = (unsigned)f2bu(vv[0]) | ((unsigned)f2bu(vv[1]) << 16);
                u.y = (unsigned)f2bu(vv[2]) | ((unsigned)f2bu(vv[3]) << 16);
                *(uint2*)((unsigned short*)d.dst + (size_t)pcol * d.Mp + mb) = u;
            } else { // 5
#pragma unroll
                for (int r = 0; r < 4; ++r) {
                    const int m = mb + r;
                    if (m < 144) {
                        float v = vv[r] + ((float*)d.dst2)[(size_t)pcol * 144 + m];
                        if (isbf) ((unsigned short*)d.dst)[(size_t)m * NPIX + pcol] = f2bu(v);
                        else      ((float*)d.dst)[(size_t)m * NPIX + pcol] = v;
                    }
                }
            }
        }
    }
}

// ---------------- conv6: static-unrolled ----------------
__global__ __launch_bounds__(256) void conv6_kernel(const short* __restrict__ YF,
                                                    const float* __restrict__ cw,
                                                    float* __restrict__ py, float* __restrict__ px)
{
    const int p = blockIdx.x * 256 + threadIdx.x;
    const int o0 = blockIdx.y * 16;
    const uint4* yrow = (const uint4*)(YF + (size_t)p * 64);
    const float* wb = cw + OF_WO6 + o0 * 64;

    float acc[16];
#pragma unroll
    for (int j = 0; j < 16; ++j) acc[j] = cw[OF_BO6 + o0 + j];

#pragma unroll
    for (int c = 0; c < 8; ++c) {
        uint4 u = yrow[c];
        float a0 = __uint_as_float(u.x << 16);
        float a1 = __uint_as_float(u.x & 0xFFFF0000u);
        float a2 = __uint_as_float(u.y << 16);
        float a3 = __uint_as_float(u.y & 0xFFFF0000u);
        float a4 = __uint_as_float(u.z << 16);
        float a5 = __uint_as_float(u.z & 0xFFFF0000u);
        float a6 = __uint_as_float(u.w << 16);
        float a7 = __uint_as_float(u.w & 0xFFFF0000u);
#pragma unroll
        for (int j = 0; j < 16; ++j) {
            const float* wr = wb + j * 64 + c * 8;
            acc[j] += a0 * wr[0] + a1 * wr[1] + a2 * wr[2] + a3 * wr[3]
                    + a4 * wr[4] + a5 * wr[5] + a6 * wr[6] + a7 * wr[7];
        }
    }

    const float f_y = cw[OF_FL0 + NPIX + p];
    const float f_x = cw[OF_FL0 + p];
    const float yf = (float)(p >> 6), xf = (float)(p & 63);
#pragma unroll
    for (int j = 0; j < 16; ++j) {
        int o = o0 + j;
        float val = 10.f * tanhf(acc[j]);
        int s = o >> 1;
        int a_idx = s % 9;
        if ((o & 1) == 0) py[s * NPIX + p] = val + f_y + (float)(a_idx / 3 - 1) + yf;
        else              px[s * NPIX + p] = val + f_x + (float)(a_idx % 3 - 1) + xf;
    }
}

// ---------------- attention: branchless corners, register-cached weights/addresses ------
__device__ __forceinline__ float dot12(const bf16* __restrict__ row, const float* qv) {
    const uint2* s = (const uint2*)row;
    float d = 0.f;
#pragma unroll
    for (int c = 0; c < 3; ++c) {
        uint2 u = s[c];
        d += qv[c * 4 + 0] * __uint_as_float(u.x << 16);
        d += qv[c * 4 + 1] * __uint_as_float(u.x & 0xFFFF0000u);
        d += qv[c * 4 + 2] * __uint_as_float(u.y << 16);
        d += qv[c * 4 + 3] * __uint_as_float(u.y & 0xFFFF0000u);
    }
    return d;
}
__device__ __forceinline__ void acc12(float* ov, const bf16* __restrict__ row, float f) {
    const uint2* s = (const uint2*)row;
#pragma unroll
    for (int c = 0; c < 3; ++c) {
        uint2 u = s[c];
        ov[c * 4 + 0] += f * __uint_as_float(u.x << 16);
        ov[c * 4 + 1] += f * __uint_as_float(u.x & 0xFFFF0000u);
        ov[c * 4 + 2] += f * __uint_as_float(u.y << 16);
        ov[c * 4 + 3] += f * __uint_as_float(u.y & 0xFFFF0000u);
    }
}

__global__ __launch_bounds__(256) void attn_kernel(
    const bf16* __restrict__ qp, const bf16* __restrict__ kp,
    const bf16* __restrict__ vp, const float* __restrict__ py,
    const float* __restrict__ px, unsigned short* __restrict__ att)
{
    const int t = blockIdx.x * 256 + threadIdx.x;
    const int ch = t & 1;
    const int clip = (t >> 1) & 1;
    const int sh = (t >> 2) & 1;
    const int pp = t >> 3;
    const int m = pp >> 12;
    const int p = pp & 4095;

    float qv[12];
    {
        const uint2* s = (const uint2*)(qp + (size_t)(m * 4096 + p) * 24 + ch * 12);
#pragma unroll
        for (int c = 0; c < 3; ++c) {
            uint2 u = s[c];
            qv[c * 4 + 0] = __uint_as_float(u.x << 16);
            qv[c * 4 + 1] = __uint_as_float(u.x & 0xFFFF0000u);
            qv[c * 4 + 2] = __uint_as_float(u.y << 16);
            qv[c * 4 + 3] = __uint_as_float(u.y & 0xFFFF0000u);
        }
    }

    const int gidx = clip * 12 + m;
    const bf16* kb = kp + (size_t)gidx * 4096 * 24 + ch * 12;
    const bf16* vb = vp + (size_t)gidx * 4096 * 24 + ch * 12;
    const int sbase = gidx * 9;
    const int a0 = sh ? 5 : 0;
    const int na = sh ? 4 : 5;

    float e[5], w0s[5], w1s[5], w2s[5], w3s[5];
    int n0s[5], n1s[5], n2s[5], n3s[5];
    float mx = -1e30f;
#pragma unroll
    for (int i = 0; i < 5; ++i) {
        const int a = min(a0 + i, 8);
        const float fy = py[(sbase + a) * NPIX + p];
        const float fx = px[(sbase + a) * NPIX + p];
        const float y0f = floorf(fy), x0f = floorf(fx);
        const float wy = fy - y0f, wx = fx - x0f;
        const int iy = (int)y0f, ix = (int)x0f;
        const float vy0 = ((unsigned)iy < 64u) ? 1.f : 0.f;
        const float vy1 = ((unsigned)(iy + 1) < 64u) ? 1.f : 0.f;
        const float vx0 = ((unsigned)ix < 64u) ? 1.f : 0.f;
        const float vx1 = ((unsigned)(ix + 1) < 64u) ? 1.f : 0.f;
        const int iy0 = min(max(iy, 0), 63), iy1 = min(max(iy + 1, 0), 63);
        const int ix0 = min(max(ix, 0), 63), ix1 = min(max(ix + 1, 0), 63);
        w0s[i] = (1.f - wy) * (1.f - wx) * vy0 * vx0;
        w1s[i] = (1.f - wy) * wx * vy0 * vx1;
        w2s[i] = wy * (1.f - wx) * vy1 * vx0;
        w3s[i] = wy * wx * vy1 * vx1;
        n0s[i] = iy0 * 64 + ix0; n1s[i] = iy0 * 64 + ix1;
        n2s[i] = iy1 * 64 + ix0; n3s[i] = iy1 * 64 + ix1;
        float part = w0s[i] * dot12(kb + (size_t)n0s[i] * 24, qv)
                   + w1s[i] * dot12(kb + (size_t)n1s[i] * 24, qv)
                   + w2s[i] * dot12(kb + (size_t)n2s[i] * 24, qv)
                   + w3s[i] * dot12(kb + (size_t)n3s[i] * 24, qv);
        float full = part + __shfl_xor(part, 1, 64);
        e[i] = (i < na) ? full * 0.20412414523193154f : -1e30f;
        mx = fmaxf(mx, e[i]);
    }
    mx = fmaxf(mx, __shfl_xor(mx, 4, 64));
    mx = fmaxf(mx, __shfl_xor(mx, 2, 64));
    float sum = 0.f;
#pragma unroll
    for (int i = 0; i < 5; ++i) { e[i] = __expf(e[i] - mx); sum += e[i]; }
    sum += __shfl_xor(sum, 4, 64);
    sum += __shfl_xor(sum, 2, 64);
    const float inv = 1.f / sum;

    float ov[12];
#pragma unroll
    for (int j = 0; j < 12; ++j) ov[j] = 0.f;

#pragma unroll
    for (int i = 0; i < 5; ++i) {
        const float wa = e[i] * inv;
        acc12(ov, vb + (size_t)n0s[i] * 24, wa * w0s[i]);
        acc12(ov, vb + (size_t)n1s[i] * 24, wa * w1s[i]);
        acc12(ov, vb + (size_t)n2s[i] * 24, wa * w2s[i]);
        acc12(ov, vb + (size_t)n3s[i] * 24, wa * w3s[i]);
    }
#pragma unroll
    for (int j = 0; j < 12; ++j) {
        ov[j] += __shfl_xor(ov[j], 4, 64);
        ov[j] += __shfl_xor(ov[j], 2, 64);
    }
    if (clip == 0 && sh == 0) {
        unsigned short* ab = att + (size_t)p * 288 + m * 24 + ch * 12;
#pragma unroll
        for (int c = 0; c < 3; ++c) {
            uint2 u;
            u.x = (unsigned)f2bu(ov[c * 4 + 0]) | ((unsigned)f2bu(ov[c * 4 + 1]) << 16);
            u.y = (unsigned)f2bu(ov[c * 4 + 2]) | ((unsigned)f2bu(ov[c * 4 + 3]) << 16);
            ((uint2*)ab)[c] = u;
        }
    }
}

// ---------------- diagnostic ----------------
__global__ void diag_kernel(float* __restrict__ out, int n, float v)
{
    int i = blockIdx.x * 256 + threadIdx.x;
    if (i < n) out[i] = (i == 0 ? v : 0.f);
}

extern "C" void kernel_launch(void* const* d_in, const int* in_sizes, int n_in,
                              void* d_out, int out_size, void* d_ws, size_t ws_size,
                              hipStream_t stream)
{
    const size_t REQUIRED = 75000000;
    if (ws_size < REQUIRED) {
        float code = 1000.0f + (float)(ws_size >> 20);
        diag_kernel<<<dim3((out_size + 255) / 256), 256, 0, stream>>>((float*)d_out, out_size, code);
        return;
    }

    char* W = (char*)d_ws;
    short* wsS = (short*)W;
    float* cw = (float*)(W + 64);

    short* conv1w = wsS + 1000000;
    short* conv3w[4] = { wsS + 1028672, wsS + 1065536, wsS + 1102400, wsS + 1139264 };
    short* wqb = wsS + 1176128, *wkb = wsS + 1222208, *wvb = wsS + 1268288;
    short* wpS = wsS + 1314368, *wm1S = wsS + 1360448, *wm2S = wsS + 1406528;

    short* XS = (short*)(W + 16777216);
    short* X1 = (short*)(W + 25165824);
    bf16*  QP = (bf16*)(W + 33554432);
    bf16*  KP = (bf16*)(W + 36700160);
    bf16*  VP = (bf16*)(W + 41943040);
    short* Y0 = (short*)(W + 50331648);
    short* Y1 = (short*)(W + 50855936);
    short* YF = (short*)(W + 51380224);
    float* PY = (float*)(W + 54525952);
    float* PX = (float*)(W + 58064896);
    unsigned short* ATT = (unsigned short*)(W + 62914560);
    short* OPM = (short*)(W + 67108864);
    float* O32 = (float*)(W + 68419584);
    short* M1  = (short*)(W + 71303168);

    const unsigned short* qraw = (const unsigned short*)d_in[0];

    // 1. convert + stage + prepack (fused)
    CArgs ca;
    const int srcidx[26] = {7,8,9,10,11,12,13,14,15,16,17,18,19,20,21,22,23,24,25,26,27,28,29,30,5,6};
    const int dsto[26]   = {0,OF_BO1,27968,OF_BO2,64896,OF_BO3,101824,OF_BO4,138752,OF_BO5,
                            OF_WO6,OF_BO6,203760,OF_BQ,245520,OF_BK,287280,OF_BV,329040,OF_BP,
                            370656,OF_BM1,412416,OF_BM2,OF_FL0,462224};
    for (int i = 0; i < 26; ++i) {
        ca.src[i] = d_in[srcidx[i]];
        ca.dstoff[i] = dsto[i];
        ca.n[i] = in_sizes[srcidx[i]];
    }
    PPArgs pp;
    pp.j[0]  = { d_in[7],  1000000, 64, 448, 436, 64,  436, 0 };
    pp.j[1]  = { d_in[9],  1028672, 64, 576, 576, 64,  576, 2 };
    pp.j[2]  = { d_in[11], 1065536, 64, 576, 576, 64,  576, 2 };
    pp.j[3]  = { d_in[13], 1102400, 64, 576, 576, 64,  576, 2 };
    pp.j[4]  = { d_in[15], 1139264, 64, 576, 576, 64,  576, 2 };
    pp.j[5]  = { d_in[19], 1176128, 288, 160, 144, 288, 288, 1 };
    pp.j[6]  = { d_in[21], 1222208, 288, 160, 144, 288, 288, 1 };
    pp.j[7]  = { d_in[23], 1268288, 288, 160, 144, 288, 288, 1 };
    pp.j[8]  = { d_in[25], 1314368, 160, 288, 288, 144, 144, 1 };
    pp.j[9]  = { d_in[27], 1360448, 288, 160, 144, 288, 288, 1 };
    pp.j[10] = { d_in[29], 1406528, 160, 288, 288, 144, 144, 1 };
    misc_kernel<<<dim3(16, 51), 256, 0, stream>>>(ca, pp, d_in[0], d_in[1], d_in[2], d_in[3],
                                                  d_in[4], d_in[5], d_in[6], cw, XS, X1, wsS);

    // 2. proj x5 (one dispatch, KP=160 unrolled)
    GemmDesc5 g3;
    const short* Xz[5] = { XS, XS + 655360, XS + 1310720, XS + 1966080, XS + 2621440 };
    const short* Az[5] = { wqb, wkb, wkb, wvb, wvb };
    const float* Bz[5] = { cw + OF_BQ, cw + OF_BK, cw + OF_BK, cw + OF_BV, cw + OF_BV };
    bf16* Dz[5] = { QP, KP, KP, VP, VP };
    const int Gz[5] = { 0, 0, 12, 0, 12 };
    for (int z = 0; z < 5; ++z)
        g3.d[z] = { Az[z], Xz[z], Bz[z], Dz[z], nullptr, qraw, 288, 288, 1, Gz[z], 1152 };
    gemm_kernel<2, 2, 0, 160><<<dim3(288, 1, 5), 256, 0, stream>>>(g3);

    // 3. conv1 (KP=448, 1024 waves)
    GemmDesc5 g1;
    g1.d[0] = { conv1w, X1, cw + OF_BO1, Y0, nullptr, qraw, 64, 64, 0, 0, 1024 };
    gemm_kernel<1, 1, 0, 448><<<dim3(256, 1, 1), 256, 0, stream>>>(g1);

    // 4-7. conv3 chain, implicit-im2col GEMMs (KP=576 unrolled, 1024 waves)
    const float* cb[4] = { cw + OF_BO2, cw + OF_BO3, cw + OF_BO4, cw + OF_BO5 };
    short* cin[4] = { Y0, Y1, Y0, Y1 };
    short* coutp[4] = { Y1, Y0, Y1, YF };
    for (int i = 0; i < 4; ++i) {
        GemmDesc5 gc;
        gc.d[0] = { conv3w[i], cin[i], cb[i], coutp[i], nullptr, qraw, 64, 64, 0, 0, 1024 };
        gemm_kernel<1, 1, 1, 576><<<dim3(256, 1, 1), 256, 0, stream>>>(gc);
    }

    // 8. conv6 -> py/px
    conv6_kernel<<<dim3(16, 27), 256, 0, stream>>>(YF, cw, PY, PX);

    // 9. attention
    attn_kernel<<<dim3(1536), 256, 0, stream>>>(QP, KP, VP, PY, PX, ATT);

    // 10. wp GEMM (KP=288)
    GemmDesc5 gwp;
    gwp.d[0] = { wpS, (const short*)ATT, cw + OF_BP, OPM, O32, qraw, 160, 144, 3, 0, 640 };
    gemm_kernel<2, 2, 0, 288><<<dim3(160, 1, 1), 256, 0, stream>>>(gwp);

    // 11. wm1 GEMM + gelu (KP=160)
    GemmDesc5 gm1;
    gm1.d[0] = { wm1S, OPM, cw + OF_BM1, M1, nullptr, qraw, 288, 288, 4, 0, 1152 };
    gemm_kernel<2, 2, 0, 160><<<dim3(288, 1, 1), 256, 0, stream>>>(gm1);

    // 12. wm2 GEMM + residual -> d_out (KP=288)
    GemmDesc5 gm2;
    gm2.d[0] = { wm2S, M1, cw + OF_BM2, d_out, O32, qraw, 160, 144, 5, 0, 640 };
    gemm_kernel<2, 2, 0, 288><<<dim3(160, 1, 1), 256, 0, stream>>>(gm2);
}